// Round 9
// baseline (14561.856 us; speedup 1.0000x reference)
//
#include <hip/hip_runtime.h>
#include <hip/hip_bf16.h>
#include <math.h>

#define B 64
#define T 160
#define P 196
#define ENC 2048
#define ATT 512
#define EMB 512
#define HID 1024
#define KTOT 3584   // EMB + ENC + HID
#define N2 2560     // ATT + ENC
#define KT4 112     // KTOT/32
#define NTHR 1024
#define NBLK 256
#define NGRP 16
#define GRPSZ (NBLK/NGRP)

typedef __attribute__((ext_vector_type(8))) short bf16x8;
typedef __attribute__((ext_vector_type(4))) float f32x4;

__device__ __forceinline__ float sigm(float x){ return 1.0f/(1.0f+__expf(-x)); }
__device__ __forceinline__ float bfu(short s){ return __uint_as_float(((unsigned)(unsigned short)s) << 16); }

// hierarchical grid barrier: 16 group counters (1KB apart) + top counter.
// group g = blockIdx.x & 15 (16 blocks/group, same-XCD). Monotone counters, round k.
__device__ __forceinline__ void gbar(unsigned* bar, unsigned k){
    __syncthreads();
    if (threadIdx.x == 0){
        __threadfence();                                   // release our writes
        unsigned g = blockIdx.x & (NGRP-1);
        unsigned* gcnt = bar + g*256;                      // 1KB apart
        unsigned* top  = bar + NGRP*256;
        unsigned old = __hip_atomic_fetch_add(gcnt, 1u, __ATOMIC_RELAXED, __HIP_MEMORY_SCOPE_AGENT);
        if (old == (k + 1u)*GRPSZ - 1u){                   // last in group this round
            __threadfence();
            __hip_atomic_fetch_add(top, 1u, __ATOMIC_RELAXED, __HIP_MEMORY_SCOPE_AGENT);
        }
        unsigned target = (k + 1u)*NGRP;
        while (__hip_atomic_load(top, __ATOMIC_RELAXED, __HIP_MEMORY_SCOPE_AGENT) < target){
            __builtin_amdgcn_s_sleep(2);
        }
        __threadfence();                                   // acquire
    }
    __syncthreads();
}

// ---------- sort: stable descending by lens ----------
__global__ void k_sort(const int* lens, int* idx, int* rank, unsigned* barCnt){
    __shared__ int L[B];
    int i = threadIdx.x;
    L[i] = lens[i];
    if (i <= NGRP) barCnt[i*256] = 0u;     // 16 group counters + top
    __syncthreads();
    int li = L[i];
    int r = 0;
    for (int j = 0; j < B; ++j){
        int lj = L[j];
        if (lj > li || (lj == li && j < i)) r++;
    }
    rank[i] = r;
    idx[r] = i;
}

// ---------- init h0/c0 (sorted order) + bf16 copy ----------
__global__ void k_init_hc(const float* enc_h, const float* enc_c, const int* idx,
                          float* h, float* c, __hip_bfloat16* h_bf){
    int j = blockIdx.x;
    int o = idx[j];
    for (int k = threadIdx.x; k < HID; k += blockDim.x){
        float hv = (k < 512) ? enc_h[o*512 + k] : enc_h[B*512 + o*512 + (k-512)];
        float cv = (k < 512) ? enc_c[o*512 + k] : enc_c[B*512 + o*512 + (k-512)];
        h[j*HID + k] = hv;
        c[j*HID + k] = cv;
        h_bf[j*HID + k] = __float2bfloat16(hv);
    }
}

// ---------- Wcat in per-strip MFMA-fragment order (once) ----------
__global__ void k_cvt_wcat(const float* Wih, const float* Whh, __hip_bfloat16* Wfrag){
    size_t i = (size_t)blockIdx.x*256 + threadIdx.x;   // 57,344 blocks -> 14,680,064
    int e = (int)(i & 7);
    size_t t2 = i >> 3;
    int lane = (int)(t2 & 63);
    size_t t3 = t2 >> 6;
    int kt = (int)(t3 % KT4);
    int strip = (int)(t3 / KT4);
    int n = strip*16 + (lane & 15);
    int r = (n & 3)*HID + (n >> 2);
    int k = kt*32 + (lane >> 4)*8 + e;
    float v = (k < EMB+ENC) ? Wih[(size_t)r*(EMB+ENC) + k]
                            : Whh[(size_t)r*HID + (k - EMB - ENC)];
    Wfrag[i] = __float2bfloat16(v);
}

__global__ void k_bsum(const float* bih, const float* bhh, float* bsum){
    int n = blockIdx.x*256 + threadIdx.x;
    int r = (n & 3)*HID + (n >> 2);
    bsum[n] = bih[r] + bhh[r];
}

__global__ void k_cvt_w2(const float* Wda, const float* bda, const float* Wfb, const float* bfb,
                         __hip_bfloat16* W2, float* bias2){
    int n = blockIdx.x;              // 0..2559
    const float* src = (n < ATT) ? (Wda + (size_t)n*HID) : (Wfb + (size_t)(n-ATT)*HID);
    __hip_bfloat16* dst = W2 + (size_t)n*HID;
    for (int k = threadIdx.x; k < HID; k += 256) dst[k] = __float2bfloat16(src[k]);
    if (threadIdx.x == 0) bias2[n] = (n < ATT) ? bda[n] : bfb[n-ATT];
}

__global__ void k_cvt_emb(const float* emb, __hip_bfloat16* emb_bf){
    size_t i = (size_t)blockIdx.x*256 + threadIdx.x;
    emb_bf[i] = __float2bfloat16(emb[i]);
}

__global__ void k_cvt_wea(const float* Wea, __hip_bfloat16* Wea_bf){
    int n = blockIdx.x;
    for (int k = threadIdx.x; k < ENC; k += 256)
        Wea_bf[(size_t)n*ENC + k] = __float2bfloat16(Wea[(size_t)n*ENC + k]);
}

__global__ void k_cvt_img(const float* img, const int* idx, __hip_bfloat16* img_s){
    int j = blockIdx.y;
    int o = idx[j];
    size_t off = (size_t)blockIdx.x*256 + threadIdx.x;
    img_s[(size_t)j*P*ENC + off] = __float2bfloat16(img[(size_t)o*P*ENC + off]);
}

// ---------- att1 (once, MFMA) ----------
__global__ __launch_bounds__(256) void k_att1m(const __hip_bfloat16* img_s, const __hip_bfloat16* Wea_bf,
                                               const float* bea, __hip_bfloat16* att1w){
    int m0 = blockIdx.x * 64, n0 = blockIdx.y * 64;
    int tid = threadIdx.x, w = tid >> 6, l = tid & 63, lm = l & 15, lk = l >> 4;
    const short* ap = (const short*)img_s + (size_t)(m0 + 16*w + lm)*ENC + 8*lk;
    const short* bp = (const short*)Wea_bf + (size_t)(n0 + lm)*ENC + 8*lk;
    f32x4 acc[4];
    #pragma unroll
    for (int nt=0; nt<4; ++nt) acc[nt] = (f32x4){0.f,0.f,0.f,0.f};
    #pragma unroll 4
    for (int kt = 0; kt < ENC/32; ++kt){
        bf16x8 a = *(const bf16x8*)(ap + kt*32);
        #pragma unroll
        for (int nt=0; nt<4; ++nt){
            bf16x8 bb = *(const bf16x8*)(bp + (size_t)nt*16*ENC + kt*32);
            acc[nt] = __builtin_amdgcn_mfma_f32_16x16x32_bf16(a, bb, acc[nt], 0,0,0);
        }
    }
    #pragma unroll
    for (int nt=0; nt<4; ++nt){
        int n = n0 + nt*16 + lm;
        float bv = bea[n];
        #pragma unroll
        for (int r=0; r<4; ++r){
            int m = m0 + 16*w + 4*lk + r;
            att1w[(size_t)m*ATT + n] = __float2bfloat16(acc[nt][r] + bv);
        }
    }
}

// ---------- persistent cooperative scan ----------
struct SP {
    const __hip_bfloat16 *att1w, *img_s, *emb_bf, *Wfrag, *W2;
    const float *bsum, *bias2, *wfa, *bfa;
    const int *sent, *idx, *rank, *lens;
    float *D2;
    __hip_bfloat16 *gc;
    float *hF0, *hF1, *cW;
    __hip_bfloat16 *hb0, *hb1;
    float *outH, *outA;
    unsigned *barCnt;
};

__global__ __launch_bounds__(1024, 4) void k_scan(SP p){
    __shared__ short WcatL[KT4*64*8];          // 114,688 B, fragment-ordered
    __shared__ union {
        struct { float Dp[4][64][17]; int tokL[64], lensL[64], wLs[64]; } gem;
        struct { float att2L[512]; float wfaL[512]; float red[1024]; float aL[208]; float ctxP[8][512]; } p23;
    } sh;

    int b = blockIdx.x, tid = threadIdx.x;
    int w = tid >> 6, l = tid & 63, lm = l & 15, lk = l >> 4;
    unsigned bk = 0;

    // one-time LDS fill (straight copy, frag order): 7168 bf16x8 / 1024 thr = 7
    {
        const bf16x8* src = (const bf16x8*)((const short*)p.Wfrag + (size_t)b*KT4*64*8);
        bf16x8* dst = (bf16x8*)WcatL;
        #pragma unroll
        for (int i = 0; i < KT4*64/NTHR; ++i) dst[tid + i*NTHR] = src[tid + i*NTHR];
    }
    __syncthreads();

    float bfa0 = p.bfa[0];

    for (int t = 0; t < T; ++t){
        const __hip_bfloat16* hbIn = (t & 1) ? p.hb1 : p.hb0;
        __hip_bfloat16*       hbOut = (t & 1) ? p.hb0 : p.hb1;
        const float* hFIn = (t & 1) ? p.hF1 : p.hF0;
        float*       hFOut = (t & 1) ? p.hF0 : p.hF1;

        // ---- P1: D2[64][2560] = h_bf @ W2^T + bias2 ; blocks < 160, 4-way K-split ----
        if (b < N2/16){
            int n0 = b*16;
            int rt = w & 3, kq = w >> 2;     // 4 row-tiles x 4 K-quarters
            const short* ap = (const short*)hbIn + (size_t)(16*rt + lm)*HID + kq*256 + 8*lk;
            const short* bp = (const short*)p.W2 + (size_t)(n0 + lm)*HID + kq*256 + 8*lk;
            f32x4 acc = {0.f,0.f,0.f,0.f};
            #pragma unroll
            for (int kt = 0; kt < 8; ++kt){
                bf16x8 a = *(const bf16x8*)(ap + kt*32);
                bf16x8 bb = *(const bf16x8*)(bp + kt*32);
                acc = __builtin_amdgcn_mfma_f32_16x16x32_bf16(a, bb, acc, 0,0,0);
            }
            #pragma unroll
            for (int r=0; r<4; ++r) sh.gem.Dp[kq][16*rt + 4*lk + r][lm] = acc[r];
            __syncthreads();
            int m = tid >> 4, nl = tid & 15;
            p.D2[m*N2 + n0 + nl] = sh.gem.Dp[0][m][nl] + sh.gem.Dp[1][m][nl]
                                 + sh.gem.Dp[2][m][nl] + sh.gem.Dp[3][m][nl] + p.bias2[n0 + nl];
        }
        gbar(p.barCnt, bk++);

        // ---- P23: e + softmax + context + gc ; block = (j=b&63, q=b>>6) ----
        {
            int j = b & 63, q = b >> 6;
            int o = p.idx[j], wj = p.rank[j], lj = p.lens[o];

            if (tid < 512){
                sh.p23.att2L[tid] = p.D2[j*N2 + tid];
                sh.p23.wfaL[tid]  = p.wfa[tid];
            }
            __syncthreads();

            // partial e: pp = tid&255 over rows, ah = tid>>2.. 4-way over 128 att-cols
            int pp = tid & 255, ah = tid >> 8;
            float acc = 0.f;
            if (pp < P){
                const short* ar = (const short*)p.att1w + (size_t)(j*P + pp)*ATT + ah*128;
                #pragma unroll 8
                for (int k8 = 0; k8 < 16; ++k8){
                    bf16x8 v = *(const bf16x8*)(ar + k8*8);
                    #pragma unroll
                    for (int z=0; z<8; ++z){
                        int a = ah*128 + k8*8 + z;
                        acc += fmaxf(bfu(v[z]) + sh.p23.att2L[a], 0.f) * sh.p23.wfaL[a];
                    }
                }
            }
            sh.p23.red[tid] = acc;
            __syncthreads();
            float e = -1e30f;
            if (tid < P) e = sh.p23.red[tid] + sh.p23.red[tid+256] + sh.p23.red[tid+512] + sh.p23.red[tid+768] + bfa0;
            __syncthreads();
            sh.p23.red[tid] = (tid < P) ? e : -1e30f;
            __syncthreads();
            for (int s = 512; s > 0; s >>= 1){
                if (tid < s) sh.p23.red[tid] = fmaxf(sh.p23.red[tid], sh.p23.red[tid+s]);
                __syncthreads();
            }
            float m = sh.p23.red[0];
            __syncthreads();
            float ex = (tid < P) ? __expf(e - m) : 0.f;
            sh.p23.red[tid] = ex;
            __syncthreads();
            for (int s = 512; s > 0; s >>= 1){
                if (tid < s) sh.p23.red[tid] += sh.p23.red[tid+s];
                __syncthreads();
            }
            float ssum = sh.p23.red[0];
            if (tid < P){
                float alpha = ex / ssum;
                sh.p23.aL[tid] = alpha;
                if (q == 0) p.outA[((size_t)(wj*T + t))*P + tid] = (t < lj) ? alpha : 0.f;
            }
            if (tid >= P && tid < 208) sh.p23.aL[tid] = 0.f;
            __syncthreads();

            // context quarter [q*512, q*512+512): wave w takes p = w, w+16, ... (13 iters)
            const short* ib = (const short*)p.img_s + (size_t)j*P*ENC + q*512 + l*8;
            float a8[8];
            #pragma unroll
            for (int z=0; z<8; ++z) a8[z] = 0.f;
            #pragma unroll 4
            for (int i = 0; i < 13; ++i){
                int pp2 = w + 16*i;
                int pr = (pp2 < P) ? pp2 : 0;
                bf16x8 v = *(const bf16x8*)(ib + (size_t)pr*ENC);
                float al = sh.p23.aL[pp2];
                #pragma unroll
                for (int z=0; z<8; ++z) a8[z] += al * bfu(v[z]);
            }
            if (w < 8){
                #pragma unroll
                for (int z=0; z<8; ++z) sh.p23.ctxP[w][l*8+z] = a8[z];
            }
            __syncthreads();
            if (w >= 8){
                #pragma unroll
                for (int z=0; z<8; ++z) sh.p23.ctxP[w-8][l*8+z] += a8[z];
            }
            __syncthreads();
            if (tid < 512){
                int d = tid;
                float ctx = 0.f;
                #pragma unroll
                for (int r=0; r<8; ++r) ctx += sh.p23.ctxP[r][d];
                int eg = q*512 + d;
                float gate = sigm(p.D2[j*N2 + ATT + eg]);
                p.gc[j*ENC + eg] = __float2bfloat16(gate*ctx);
            }
        }
        gbar(p.barCnt, bk++);

        // ---- P4: gates GEMM (4-way K-split, B from LDS) + LSTM + outputs ----
        {
            if (tid < 64){
                int o = p.idx[tid];
                sh.gem.tokL[tid] = p.sent[o*T + t];
                sh.gem.lensL[tid] = p.lens[o];
                sh.gem.wLs[tid] = p.rank[tid];
            }
            __syncthreads();
            int rt = w & 3, kq = w >> 2;
            int mrow = 16*rt + lm;
            int tok = sh.gem.tokL[mrow];
            const short* aEmb = (const short*)p.emb_bf + (size_t)tok*EMB + 8*lk;
            const short* aGc  = (const short*)p.gc + (size_t)mrow*ENC + 8*lk;
            const short* aH   = (const short*)hbIn + (size_t)mrow*HID + 8*lk;
            const bf16x8* BL = (const bf16x8*)WcatL;
            f32x4 acc = {0.f,0.f,0.f,0.f};
            // K quarters of 28 kt: [0,28)=emb16+gc12, [28,56)=gc, [56,84)=gc24+h4, [84,112)=h
            if (kq == 0){
                #pragma unroll 8
                for (int kt = 0; kt < 16; ++kt){
                    bf16x8 a = *(const bf16x8*)(aEmb + kt*32);
                    acc = __builtin_amdgcn_mfma_f32_16x16x32_bf16(a, BL[kt*64 + l], acc, 0,0,0);
                }
                #pragma unroll 6
                for (int kt = 16; kt < 28; ++kt){
                    bf16x8 a = *(const bf16x8*)(aGc + (kt-16)*32);
                    acc = __builtin_amdgcn_mfma_f32_16x16x32_bf16(a, BL[kt*64 + l], acc, 0,0,0);
                }
            } else if (kq == 1){
                #pragma unroll 7
                for (int kt = 28; kt < 56; ++kt){
                    bf16x8 a = *(const bf16x8*)(aGc + (kt-16)*32);
                    acc = __builtin_amdgcn_mfma_f32_16x16x32_bf16(a, BL[kt*64 + l], acc, 0,0,0);
                }
            } else if (kq == 2){
                #pragma unroll 6
                for (int kt = 56; kt < 80; ++kt){
                    bf16x8 a = *(const bf16x8*)(aGc + (kt-16)*32);
                    acc = __builtin_amdgcn_mfma_f32_16x16x32_bf16(a, BL[kt*64 + l], acc, 0,0,0);
                }
                #pragma unroll
                for (int kt = 80; kt < 84; ++kt){
                    bf16x8 a = *(const bf16x8*)(aH + (kt-80)*32);
                    acc = __builtin_amdgcn_mfma_f32_16x16x32_bf16(a, BL[kt*64 + l], acc, 0,0,0);
                }
            } else {
                #pragma unroll 7
                for (int kt = 84; kt < 112; ++kt){
                    bf16x8 a = *(const bf16x8*)(aH + (kt-80)*32);
                    acc = __builtin_amdgcn_mfma_f32_16x16x32_bf16(a, BL[kt*64 + l], acc, 0,0,0);
                }
            }
            #pragma unroll
            for (int r=0; r<4; ++r) sh.gem.Dp[kq][16*rt + 4*lk + r][lm] = acc[r];
            __syncthreads();
            if (tid < 256){
                int j2 = tid & 63, du = tid >> 6;
                int u = 4*b + du;
                float g4[4];
                #pragma unroll
                for (int g=0; g<4; ++g){
                    int nl = 4*du + g;
                    g4[g] = sh.gem.Dp[0][j2][nl] + sh.gem.Dp[1][j2][nl]
                          + sh.gem.Dp[2][j2][nl] + sh.gem.Dp[3][j2][nl] + p.bsum[16*b + nl];
                }
                float ig = sigm(g4[0]), fg = sigm(g4[1]), gg = tanhf(g4[2]), og = sigm(g4[3]);
                float cOld = p.cW[j2*HID + u];
                float cNew = fg*cOld + ig*gg;
                float hNew = og*tanhf(cNew);
                bool active = (t < sh.gem.lensL[j2]);
                float hOld = hFIn[j2*HID + u];
                float hKeep = active ? hNew : hOld;
                hFOut[j2*HID + u] = hKeep;
                hbOut[j2*HID + u] = __float2bfloat16(hKeep);
                p.cW[j2*HID + u] = active ? cNew : cOld;
                p.outH[((size_t)sh.gem.wLs[j2]*T + t)*HID + u] = active ? hNew : 0.f;
            }
        }
        gbar(p.barCnt, bk++);
    }
}

extern "C" void kernel_launch(void* const* d_in, const int* in_sizes, int n_in,
                              void* d_out, int out_size, void* d_ws, size_t ws_size,
                              hipStream_t stream) {
    const float* img   = (const float*)d_in[0];
    const int*   sent  = (const int*)  d_in[1];
    const float* enc_h = (const float*)d_in[2];
    const float* enc_c = (const float*)d_in[3];
    const int*   lens  = (const int*)  d_in[4];
    const float* emb   = (const float*)d_in[5];
    const float* Wea   = (const float*)d_in[6];
    const float* bea   = (const float*)d_in[7];
    const float* Wda   = (const float*)d_in[8];
    const float* bda   = (const float*)d_in[9];
    const float* wfa   = (const float*)d_in[10];
    const float* bfa   = (const float*)d_in[11];
    const float* Wfb   = (const float*)d_in[12];
    const float* bfb   = (const float*)d_in[13];
    const float* Wih   = (const float*)d_in[14];
    const float* bih   = (const float*)d_in[15];
    const float* Whh   = (const float*)d_in[16];
    const float* bhh   = (const float*)d_in[17];

    float* outH = (float*)d_out;                       // [B,T,HID] f32
    float* outA = outH + (size_t)B*T*HID;              // [B,T,P]  f32

    char* wsb = (char*)d_ws;
    size_t off = 0;
    int* idxW  = (int*)(wsb + off); off += 256;
    int* rankW = (int*)(wsb + off); off += 256;
    unsigned* barCnt = (unsigned*)(wsb + off); off += 32768;   // 16 group counters (1KB apart) + top
    __hip_bfloat16* att1w = (__hip_bfloat16*)(wsb + off); off += (size_t)B*P*ATT*2;       // 12.85MB
    __hip_bfloat16* img_s = (__hip_bfloat16*)(wsb + off); off += (size_t)B*P*ENC*2;       // 51.38MB
    __hip_bfloat16* emb_bf= (__hip_bfloat16*)(wsb + off); off += (size_t)10000*EMB*2;     // 10.24MB
    __hip_bfloat16* Wfrag = (__hip_bfloat16*)(wsb + off); off += (size_t)4*HID*KTOT*2;    // 29.36MB
    __hip_bfloat16* W2    = (__hip_bfloat16*)(wsb + off); off += (size_t)N2*HID*2;        // 5.24MB
    __hip_bfloat16* Wea_bf= (__hip_bfloat16*)(wsb + off); off += (size_t)ATT*ENC*2;       // 2.10MB (prologue-only)
    float* bsum  = (float*)(wsb + off); off += 4*HID*4;
    float* bias2 = (float*)(wsb + off); off += N2*4;
    float* hA    = (float*)(wsb + off); off += B*HID*4;
    float* hB    = (float*)(wsb + off); off += B*HID*4;
    float* cWs   = (float*)(wsb + off); off += B*HID*4;
    __hip_bfloat16* hbfA = (__hip_bfloat16*)(wsb + off); off += B*HID*2;
    __hip_bfloat16* hbfB = (__hip_bfloat16*)(wsb + off); off += B*HID*2;
    float* D2    = (float*)(wsb + off); off += (size_t)B*N2*4;
    __hip_bfloat16* gcW  = (__hip_bfloat16*)(wsb + off); off += B*ENC*2;

    k_sort<<<1, 64, 0, stream>>>(lens, idxW, rankW, barCnt);
    k_init_hc<<<B, 256, 0, stream>>>(enc_h, enc_c, idxW, hA, cWs, hbfA);
    k_cvt_wcat<<<57344, 256, 0, stream>>>(Wih, Whh, Wfrag);
    k_bsum<<<16, 256, 0, stream>>>(bih, bhh, bsum);
    k_cvt_w2<<<N2, 256, 0, stream>>>(Wda, bda, Wfb, bfb, W2, bias2);
    k_cvt_emb<<<20000, 256, 0, stream>>>(emb, emb_bf);
    k_cvt_wea<<<ATT, 256, 0, stream>>>(Wea, Wea_bf);
    k_cvt_img<<<dim3(P*ENC/256, B), 256, 0, stream>>>(img, idxW, img_s);
    k_att1m<<<dim3((B*P)/64, ATT/64), 256, 0, stream>>>(img_s, Wea_bf, bea, att1w);

    SP sp;
    sp.att1w = att1w; sp.img_s = img_s; sp.emb_bf = emb_bf; sp.Wfrag = Wfrag; sp.W2 = W2;
    sp.bsum = bsum; sp.bias2 = bias2; sp.wfa = wfa; sp.bfa = bfa;
    sp.sent = sent; sp.idx = idxW; sp.rank = rankW; sp.lens = lens;
    sp.D2 = D2; sp.gc = gcW;
    sp.hF0 = hA; sp.hF1 = hB; sp.cW = cWs;
    sp.hb0 = hbfA; sp.hb1 = hbfB;
    sp.outH = outH; sp.outA = outA;
    sp.barCnt = barCnt;

    void* args[] = { &sp };
    hipLaunchCooperativeKernel(reinterpret_cast<void*>(k_scan), dim3(NBLK), dim3(NTHR),
                               args, 0, stream);
}

// Round 10
// 10507.051 us; speedup vs baseline: 1.3859x; 1.3859x over previous
//
#include <hip/hip_runtime.h>
#include <hip/hip_bf16.h>
#include <math.h>

#define B 64
#define T 160
#define P 196
#define ENC 2048
#define ATT 512
#define EMB 512
#define HID 1024
#define KTOT 3584   // EMB + ENC + HID
#define N2 2560     // ATT + ENC
#define KT4 112     // KTOT/32
#define NTHR 1024
#define NBLK 256
#define NGRP 16
#define GRPSZ (NBLK/NGRP)

typedef __attribute__((ext_vector_type(8))) short bf16x8;
typedef __attribute__((ext_vector_type(4))) float f32x4;

__device__ __forceinline__ float sigm(float x){ return 1.0f/(1.0f+__expf(-x)); }
__device__ __forceinline__ float bfu(short s){ return __uint_as_float(((unsigned)(unsigned short)s) << 16); }

// ---- cache-coherent (MALL-level) data movement, no fences needed ----
__device__ __forceinline__ float ldgf(const float* p){
    return __hip_atomic_load(p, __ATOMIC_RELAXED, __HIP_MEMORY_SCOPE_AGENT);
}
__device__ __forceinline__ void stgf(float* p, float v){
    __hip_atomic_store(p, v, __ATOMIC_RELAXED, __HIP_MEMORY_SCOPE_AGENT);
}
__device__ __forceinline__ void stgu(unsigned* p, unsigned v){
    __hip_atomic_store(p, v, __ATOMIC_RELAXED, __HIP_MEMORY_SCOPE_AGENT);
}
__device__ __forceinline__ bf16x8 ldg16(const short* p){
    union { bf16x8 v; unsigned long long q[2]; } u;
    u.q[0] = __hip_atomic_load((const unsigned long long*)p,     __ATOMIC_RELAXED, __HIP_MEMORY_SCOPE_AGENT);
    u.q[1] = __hip_atomic_load((const unsigned long long*)(p+4), __ATOMIC_RELAXED, __HIP_MEMORY_SCOPE_AGENT);
    return u.v;
}
__device__ __forceinline__ unsigned pkbf(float a, float b){
    unsigned ua = (unsigned)__bfloat16_as_ushort(__float2bfloat16(a));
    unsigned ub = (unsigned)__bfloat16_as_ushort(__float2bfloat16(b));
    return ua | (ub << 16);
}

// fence-free hierarchical grid barrier: per-wave vmcnt drain, then counters.
__device__ __forceinline__ void gbar(unsigned* bar, unsigned k){
    asm volatile("s_waitcnt vmcnt(0)" ::: "memory");   // our stores (incl. agent-scope) complete
    __syncthreads();
    if (threadIdx.x == 0){
        unsigned g = blockIdx.x & (NGRP-1);
        unsigned* gcnt = bar + g*256;
        unsigned* top  = bar + NGRP*256;
        unsigned old = __hip_atomic_fetch_add(gcnt, 1u, __ATOMIC_RELAXED, __HIP_MEMORY_SCOPE_AGENT);
        if (old == (k + 1u)*GRPSZ - 1u){
            __hip_atomic_fetch_add(top, 1u, __ATOMIC_RELAXED, __HIP_MEMORY_SCOPE_AGENT);
        }
        unsigned target = (k + 1u)*NGRP;
        while (__hip_atomic_load(top, __ATOMIC_RELAXED, __HIP_MEMORY_SCOPE_AGENT) < target){
            __builtin_amdgcn_s_sleep(2);
        }
    }
    __syncthreads();
    asm volatile("" ::: "memory");                     // no compiler hoisting of loads above spin
}

// ---------- sort: stable descending by lens ----------
__global__ void k_sort(const int* lens, int* idx, int* rank, unsigned* barCnt){
    __shared__ int L[B];
    int i = threadIdx.x;
    L[i] = lens[i];
    if (i <= NGRP) barCnt[i*256] = 0u;     // 16 group counters + top
    __syncthreads();
    int li = L[i];
    int r = 0;
    for (int j = 0; j < B; ++j){
        int lj = L[j];
        if (lj > li || (lj == li && j < i)) r++;
    }
    rank[i] = r;
    idx[r] = i;
}

// ---------- init h0/c0 (sorted order) + bf16 copy ----------
__global__ void k_init_hc(const float* enc_h, const float* enc_c, const int* idx,
                          float* h, float* c, __hip_bfloat16* h_bf){
    int j = blockIdx.x;
    int o = idx[j];
    for (int k = threadIdx.x; k < HID; k += blockDim.x){
        float hv = (k < 512) ? enc_h[o*512 + k] : enc_h[B*512 + o*512 + (k-512)];
        float cv = (k < 512) ? enc_c[o*512 + k] : enc_c[B*512 + o*512 + (k-512)];
        h[j*HID + k] = hv;
        c[j*HID + k] = cv;
        h_bf[j*HID + k] = __float2bfloat16(hv);
    }
}

// ---------- Wcat in per-strip MFMA-fragment order (once) ----------
__global__ void k_cvt_wcat(const float* Wih, const float* Whh, __hip_bfloat16* Wfrag){
    size_t i = (size_t)blockIdx.x*256 + threadIdx.x;   // 57,344 blocks -> 14,680,064
    int e = (int)(i & 7);
    size_t t2 = i >> 3;
    int lane = (int)(t2 & 63);
    size_t t3 = t2 >> 6;
    int kt = (int)(t3 % KT4);
    int strip = (int)(t3 / KT4);
    int n = strip*16 + (lane & 15);
    int r = (n & 3)*HID + (n >> 2);
    int k = kt*32 + (lane >> 4)*8 + e;
    float v = (k < EMB+ENC) ? Wih[(size_t)r*(EMB+ENC) + k]
                            : Whh[(size_t)r*HID + (k - EMB - ENC)];
    Wfrag[i] = __float2bfloat16(v);
}

__global__ void k_bsum(const float* bih, const float* bhh, float* bsum){
    int n = blockIdx.x*256 + threadIdx.x;
    int r = (n & 3)*HID + (n >> 2);
    bsum[n] = bih[r] + bhh[r];
}

__global__ void k_cvt_w2(const float* Wda, const float* bda, const float* Wfb, const float* bfb,
                         __hip_bfloat16* W2, float* bias2){
    int n = blockIdx.x;              // 0..2559
    const float* src = (n < ATT) ? (Wda + (size_t)n*HID) : (Wfb + (size_t)(n-ATT)*HID);
    __hip_bfloat16* dst = W2 + (size_t)n*HID;
    for (int k = threadIdx.x; k < HID; k += 256) dst[k] = __float2bfloat16(src[k]);
    if (threadIdx.x == 0) bias2[n] = (n < ATT) ? bda[n] : bfb[n-ATT];
}

__global__ void k_cvt_emb(const float* emb, __hip_bfloat16* emb_bf){
    size_t i = (size_t)blockIdx.x*256 + threadIdx.x;
    emb_bf[i] = __float2bfloat16(emb[i]);
}

__global__ void k_cvt_wea(const float* Wea, __hip_bfloat16* Wea_bf){
    int n = blockIdx.x;
    for (int k = threadIdx.x; k < ENC; k += 256)
        Wea_bf[(size_t)n*ENC + k] = __float2bfloat16(Wea[(size_t)n*ENC + k]);
}

__global__ void k_cvt_img(const float* img, const int* idx, __hip_bfloat16* img_s){
    int j = blockIdx.y;
    int o = idx[j];
    size_t off = (size_t)blockIdx.x*256 + threadIdx.x;
    img_s[(size_t)j*P*ENC + off] = __float2bfloat16(img[(size_t)o*P*ENC + off]);
}

// ---------- att1 (once, MFMA) ----------
__global__ __launch_bounds__(256) void k_att1m(const __hip_bfloat16* img_s, const __hip_bfloat16* Wea_bf,
                                               const float* bea, __hip_bfloat16* att1w){
    int m0 = blockIdx.x * 64, n0 = blockIdx.y * 64;
    int tid = threadIdx.x, w = tid >> 6, l = tid & 63, lm = l & 15, lk = l >> 4;
    const short* ap = (const short*)img_s + (size_t)(m0 + 16*w + lm)*ENC + 8*lk;
    const short* bp = (const short*)Wea_bf + (size_t)(n0 + lm)*ENC + 8*lk;
    f32x4 acc[4];
    #pragma unroll
    for (int nt=0; nt<4; ++nt) acc[nt] = (f32x4){0.f,0.f,0.f,0.f};
    #pragma unroll 4
    for (int kt = 0; kt < ENC/32; ++kt){
        bf16x8 a = *(const bf16x8*)(ap + kt*32);
        #pragma unroll
        for (int nt=0; nt<4; ++nt){
            bf16x8 bb = *(const bf16x8*)(bp + (size_t)nt*16*ENC + kt*32);
            acc[nt] = __builtin_amdgcn_mfma_f32_16x16x32_bf16(a, bb, acc[nt], 0,0,0);
        }
    }
    #pragma unroll
    for (int nt=0; nt<4; ++nt){
        int n = n0 + nt*16 + lm;
        float bv = bea[n];
        #pragma unroll
        for (int r=0; r<4; ++r){
            int m = m0 + 16*w + 4*lk + r;
            att1w[(size_t)m*ATT + n] = __float2bfloat16(acc[nt][r] + bv);
        }
    }
}

// ---------- persistent cooperative scan ----------
struct SP {
    const __hip_bfloat16 *att1w, *img_s, *emb_bf, *Wfrag, *W2;
    const float *bsum, *bias2, *wfa, *bfa;
    const int *sent, *idx, *rank, *lens;
    float *D2;
    __hip_bfloat16 *gc;
    float *hF0, *hF1, *cW;
    __hip_bfloat16 *hb0, *hb1;
    float *outH, *outA;
    unsigned *barCnt;
};

__global__ __launch_bounds__(1024, 4) void k_scan(SP p){
    __shared__ short WcatL[KT4*64*8];          // 114,688 B, fragment-ordered
    __shared__ union {
        struct { float Dp[4][64][17]; float hS[64][4]; int tokL[64], lensL[64], wLs[64]; } gem;
        struct { float att2L[512]; float wfaL[512]; float red[1024]; float aL[208]; float ctxP[8][512]; } p23;
    } sh;

    int b = blockIdx.x, tid = threadIdx.x;
    int w = tid >> 6, l = tid & 63, lm = l & 15, lk = l >> 4;
    unsigned bk = 0;

    // one-time LDS fill (straight copy, frag order)
    {
        const bf16x8* src = (const bf16x8*)((const short*)p.Wfrag + (size_t)b*KT4*64*8);
        bf16x8* dst = (bf16x8*)WcatL;
        #pragma unroll
        for (int i = 0; i < KT4*64/NTHR; ++i) dst[tid + i*NTHR] = src[tid + i*NTHR];
    }
    __syncthreads();

    float bfa0 = p.bfa[0];

    for (int t = 0; t < T; ++t){
        const __hip_bfloat16* hbIn = (t & 1) ? p.hb1 : p.hb0;
        __hip_bfloat16*       hbOut = (t & 1) ? p.hb0 : p.hb1;
        const float* hFIn = (t & 1) ? p.hF1 : p.hF0;
        float*       hFOut = (t & 1) ? p.hF0 : p.hF1;

        // ---- P1: D2[64][2560] = h_bf @ W2^T + bias2 ; blocks < 160, 4-way K-split ----
        if (b < N2/16){
            int n0 = b*16;
            int rt = w & 3, kq = w >> 2;     // 4 row-tiles x 4 K-quarters
            const short* ap = (const short*)hbIn + (size_t)(16*rt + lm)*HID + kq*256 + 8*lk;
            const short* bp = (const short*)p.W2 + (size_t)(n0 + lm)*HID + kq*256 + 8*lk;
            f32x4 acc = {0.f,0.f,0.f,0.f};
            #pragma unroll
            for (int kt = 0; kt < 8; ++kt){
                bf16x8 a = ldg16(ap + kt*32);
                bf16x8 bb = *(const bf16x8*)(bp + kt*32);
                acc = __builtin_amdgcn_mfma_f32_16x16x32_bf16(a, bb, acc, 0,0,0);
            }
            #pragma unroll
            for (int r=0; r<4; ++r) sh.gem.Dp[kq][16*rt + 4*lk + r][lm] = acc[r];
            __syncthreads();
            int m = tid >> 4, nl = tid & 15;
            stgf(&p.D2[m*N2 + n0 + nl],
                 sh.gem.Dp[0][m][nl] + sh.gem.Dp[1][m][nl]
               + sh.gem.Dp[2][m][nl] + sh.gem.Dp[3][m][nl] + p.bias2[n0 + nl]);
        }
        gbar(p.barCnt, bk++);

        // ---- P23: e + softmax + context + gc ; block = (j=b&63, q=b>>6) ----
        {
            int j = b & 63, q = b >> 6;
            int o = p.idx[j], wj = p.rank[j], lj = p.lens[o];
            if (t < lj){
                if (tid < 512){
                    sh.p23.att2L[tid] = ldgf(&p.D2[j*N2 + tid]);
                    sh.p23.wfaL[tid]  = p.wfa[tid];
                }
                __syncthreads();

                int pp = tid & 255, ah = tid >> 8;
                float acc = 0.f;
                if (pp < P){
                    const short* ar = (const short*)p.att1w + (size_t)(j*P + pp)*ATT + ah*128;
                    #pragma unroll 8
                    for (int k8 = 0; k8 < 16; ++k8){
                        bf16x8 v = *(const bf16x8*)(ar + k8*8);
                        #pragma unroll
                        for (int z=0; z<8; ++z){
                            int a = ah*128 + k8*8 + z;
                            acc += fmaxf(bfu(v[z]) + sh.p23.att2L[a], 0.f) * sh.p23.wfaL[a];
                        }
                    }
                }
                sh.p23.red[tid] = acc;
                __syncthreads();
                float e = -1e30f;
                if (tid < P) e = sh.p23.red[tid] + sh.p23.red[tid+256] + sh.p23.red[tid+512] + sh.p23.red[tid+768] + bfa0;
                __syncthreads();
                sh.p23.red[tid] = (tid < P) ? e : -1e30f;
                __syncthreads();
                for (int s = 512; s > 0; s >>= 1){
                    if (tid < s) sh.p23.red[tid] = fmaxf(sh.p23.red[tid], sh.p23.red[tid+s]);
                    __syncthreads();
                }
                float m = sh.p23.red[0];
                __syncthreads();
                float ex = (tid < P) ? __expf(e - m) : 0.f;
                sh.p23.red[tid] = ex;
                __syncthreads();
                for (int s = 512; s > 0; s >>= 1){
                    if (tid < s) sh.p23.red[tid] += sh.p23.red[tid+s];
                    __syncthreads();
                }
                float ssum = sh.p23.red[0];
                if (tid < P){
                    float alpha = ex / ssum;
                    sh.p23.aL[tid] = alpha;
                    if (q == 0) p.outA[((size_t)(wj*T + t))*P + tid] = alpha;
                }
                if (tid >= P && tid < 208) sh.p23.aL[tid] = 0.f;
                __syncthreads();

                // context quarter [q*512, q*512+512): wave w takes p = w, w+16, ...
                const short* ib = (const short*)p.img_s + (size_t)j*P*ENC + q*512 + l*8;
                float a8[8];
                #pragma unroll
                for (int z=0; z<8; ++z) a8[z] = 0.f;
                #pragma unroll 4
                for (int i = 0; i < 13; ++i){
                    int pp2 = w + 16*i;
                    int pr = (pp2 < P) ? pp2 : 0;
                    bf16x8 v = *(const bf16x8*)(ib + (size_t)pr*ENC);
                    float al = sh.p23.aL[pp2];
                    #pragma unroll
                    for (int z=0; z<8; ++z) a8[z] += al * bfu(v[z]);
                }
                if (w < 8){
                    #pragma unroll
                    for (int z=0; z<8; ++z) sh.p23.ctxP[w][l*8+z] = a8[z];
                }
                __syncthreads();
                if (w >= 8){
                    #pragma unroll
                    for (int z=0; z<8; ++z) sh.p23.ctxP[w-8][l*8+z] += a8[z];
                }
                __syncthreads();
                if (tid < 256){
                    int d0 = 2*tid;
                    float c0 = 0.f, c1 = 0.f;
                    #pragma unroll
                    for (int r=0; r<8; ++r){ c0 += sh.p23.ctxP[r][d0]; c1 += sh.p23.ctxP[r][d0+1]; }
                    int eg0 = q*512 + d0;
                    float g0 = sigm(ldgf(&p.D2[j*N2 + ATT + eg0]));
                    float g1 = sigm(ldgf(&p.D2[j*N2 + ATT + eg0 + 1]));
                    stgu((unsigned*)((short*)p.gc + j*ENC + eg0), pkbf(g0*c0, g1*c1));
                }
            } else {
                // finished sentence: outputs are zeros; h/c held; stale gc is fine (deterministic)
                if (q == 0 && tid < P) p.outA[((size_t)(wj*T + t))*P + tid] = 0.f;
            }
        }
        gbar(p.barCnt, bk++);

        // ---- P4: gates GEMM (4-way K-split, B from LDS) + LSTM + outputs ----
        {
            if (tid < 64){
                int o = p.idx[tid];
                sh.gem.tokL[tid] = p.sent[o*T + t];
                sh.gem.lensL[tid] = p.lens[o];
                sh.gem.wLs[tid] = p.rank[tid];
            }
            __syncthreads();
            int rt = w & 3, kq = w >> 2;
            int mrow = 16*rt + lm;
            int tok = sh.gem.tokL[mrow];
            const short* aEmb = (const short*)p.emb_bf + (size_t)tok*EMB + 8*lk;
            const short* aGc  = (const short*)p.gc + (size_t)mrow*ENC + 8*lk;
            const short* aH   = (const short*)hbIn + (size_t)mrow*HID + 8*lk;
            const bf16x8* BL = (const bf16x8*)WcatL;
            f32x4 acc = {0.f,0.f,0.f,0.f};
            // K quarters of 28 kt: [0,28)=emb16+gc12, [28,56)=gc, [56,84)=gc24+h4, [84,112)=h
            if (kq == 0){
                #pragma unroll 8
                for (int kt = 0; kt < 16; ++kt){
                    bf16x8 a = *(const bf16x8*)(aEmb + kt*32);
                    acc = __builtin_amdgcn_mfma_f32_16x16x32_bf16(a, BL[kt*64 + l], acc, 0,0,0);
                }
                #pragma unroll 6
                for (int kt = 16; kt < 28; ++kt){
                    bf16x8 a = ldg16(aGc + (kt-16)*32);
                    acc = __builtin_amdgcn_mfma_f32_16x16x32_bf16(a, BL[kt*64 + l], acc, 0,0,0);
                }
            } else if (kq == 1){
                #pragma unroll 7
                for (int kt = 28; kt < 56; ++kt){
                    bf16x8 a = ldg16(aGc + (kt-16)*32);
                    acc = __builtin_amdgcn_mfma_f32_16x16x32_bf16(a, BL[kt*64 + l], acc, 0,0,0);
                }
            } else if (kq == 2){
                #pragma unroll 6
                for (int kt = 56; kt < 80; ++kt){
                    bf16x8 a = ldg16(aGc + (kt-16)*32);
                    acc = __builtin_amdgcn_mfma_f32_16x16x32_bf16(a, BL[kt*64 + l], acc, 0,0,0);
                }
                #pragma unroll
                for (int kt = 80; kt < 84; ++kt){
                    bf16x8 a = ldg16(aH + (kt-80)*32);
                    acc = __builtin_amdgcn_mfma_f32_16x16x32_bf16(a, BL[kt*64 + l], acc, 0,0,0);
                }
            } else {
                #pragma unroll 7
                for (int kt = 84; kt < 112; ++kt){
                    bf16x8 a = ldg16(aH + (kt-80)*32);
                    acc = __builtin_amdgcn_mfma_f32_16x16x32_bf16(a, BL[kt*64 + l], acc, 0,0,0);
                }
            }
            #pragma unroll
            for (int r=0; r<4; ++r) sh.gem.Dp[kq][16*rt + 4*lk + r][lm] = acc[r];
            __syncthreads();
            if (tid < 256){
                int j2 = tid & 63, du = tid >> 6;
                int u = 4*b + du;
                float g4[4];
                #pragma unroll
                for (int g=0; g<4; ++g){
                    int nl = 4*du + g;
                    g4[g] = sh.gem.Dp[0][j2][nl] + sh.gem.Dp[1][j2][nl]
                          + sh.gem.Dp[2][j2][nl] + sh.gem.Dp[3][j2][nl] + p.bsum[16*b + nl];
                }
                float ig = sigm(g4[0]), fg = sigm(g4[1]), gg = tanhf(g4[2]), og = sigm(g4[3]);
                float cOld = p.cW[j2*HID + u];
                float cNew = fg*cOld + ig*gg;
                float hNew = og*tanhf(cNew);
                bool active = (t < sh.gem.lensL[j2]);
                float hOld = hFIn[j2*HID + u];
                float hKeep = active ? hNew : hOld;
                hFOut[j2*HID + u] = hKeep;
                sh.gem.hS[j2][du] = hKeep;
                p.cW[j2*HID + u] = active ? cNew : cOld;
                p.outH[((size_t)sh.gem.wLs[j2]*T + t)*HID + u] = active ? hNew : 0.f;
            }
            __syncthreads();
            if (tid < 128){
                int j2 = tid & 63, dp = tid >> 6;    // dp in {0,1}
                int u0 = 4*b + 2*dp;
                stgu((unsigned*)((short*)hbOut + j2*HID + u0),
                     pkbf(sh.gem.hS[j2][2*dp], sh.gem.hS[j2][2*dp+1]));
            }
        }
        gbar(p.barCnt, bk++);
    }
}

extern "C" void kernel_launch(void* const* d_in, const int* in_sizes, int n_in,
                              void* d_out, int out_size, void* d_ws, size_t ws_size,
                              hipStream_t stream) {
    const float* img   = (const float*)d_in[0];
    const int*   sent  = (const int*)  d_in[1];
    const float* enc_h = (const float*)d_in[2];
    const float* enc_c = (const float*)d_in[3];
    const int*   lens  = (const int*)  d_in[4];
    const float* emb   = (const float*)d_in[5];
    const float* Wea   = (const float*)d_in[6];
    const float* bea   = (const float*)d_in[7];
    const float* Wda   = (const float*)d_in[8];
    const float* bda   = (const float*)d_in[9];
    const float* wfa   = (const float*)d_in[10];
    const float* bfa   = (const float*)d_in[11];
    const float* Wfb   = (const float*)d_in[12];
    const float* bfb   = (const float*)d_in[13];
    const float* Wih   = (const float*)d_in[14];
    const float* bih   = (const float*)d_in[15];
    const float* Whh   = (const float*)d_in[16];
    const float* bhh   = (const float*)d_in[17];

    float* outH = (float*)d_out;                       // [B,T,HID] f32
    float* outA = outH + (size_t)B*T*HID;              // [B,T,P]  f32

    char* wsb = (char*)d_ws;
    size_t off = 0;
    int* idxW  = (int*)(wsb + off); off += 256;
    int* rankW = (int*)(wsb + off); off += 256;
    unsigned* barCnt = (unsigned*)(wsb + off); off += 32768;   // 16 group counters (1KB apart) + top
    __hip_bfloat16* att1w = (__hip_bfloat16*)(wsb + off); off += (size_t)B*P*ATT*2;       // 12.85MB
    __hip_bfloat16* img_s = (__hip_bfloat16*)(wsb + off); off += (size_t)B*P*ENC*2;       // 51.38MB
    __hip_bfloat16* emb_bf= (__hip_bfloat16*)(wsb + off); off += (size_t)10000*EMB*2;     // 10.24MB
    __hip_bfloat16* Wfrag = (__hip_bfloat16*)(wsb + off); off += (size_t)4*HID*KTOT*2;    // 29.36MB
    __hip_bfloat16* W2    = (__hip_bfloat16*)(wsb + off); off += (size_t)N2*HID*2;        // 5.24MB
    __hip_bfloat16* Wea_bf= (__hip_bfloat16*)(wsb + off); off += (size_t)ATT*ENC*2;       // 2.10MB (prologue-only)
    float* bsum  = (float*)(wsb + off); off += 4*HID*4;
    float* bias2 = (float*)(wsb + off); off += N2*4;
    float* hA    = (float*)(wsb + off); off += B*HID*4;
    float* hB    = (float*)(wsb + off); off += B*HID*4;
    float* cWs   = (float*)(wsb + off); off += B*HID*4;
    __hip_bfloat16* hbfA = (__hip_bfloat16*)(wsb + off); off += B*HID*2;
    __hip_bfloat16* hbfB = (__hip_bfloat16*)(wsb + off); off += B*HID*2;
    float* D2    = (float*)(wsb + off); off += (size_t)B*N2*4;
    __hip_bfloat16* gcW  = (__hip_bfloat16*)(wsb + off); off += B*ENC*2;

    k_sort<<<1, 64, 0, stream>>>(lens, idxW, rankW, barCnt);
    k_init_hc<<<B, 256, 0, stream>>>(enc_h, enc_c, idxW, hA, cWs, hbfA);
    k_cvt_wcat<<<57344, 256, 0, stream>>>(Wih, Whh, Wfrag);
    k_bsum<<<16, 256, 0, stream>>>(bih, bhh, bsum);
    k_cvt_w2<<<N2, 256, 0, stream>>>(Wda, bda, Wfb, bfb, W2, bias2);
    k_cvt_emb<<<20000, 256, 0, stream>>>(emb, emb_bf);
    k_cvt_wea<<<ATT, 256, 0, stream>>>(Wea, Wea_bf);
    k_cvt_img<<<dim3(P*ENC/256, B), 256, 0, stream>>>(img, idxW, img_s);
    k_att1m<<<dim3((B*P)/64, ATT/64), 256, 0, stream>>>(img_s, Wea_bf, bea, att1w);

    SP sp;
    sp.att1w = att1w; sp.img_s = img_s; sp.emb_bf = emb_bf; sp.Wfrag = Wfrag; sp.W2 = W2;
    sp.bsum = bsum; sp.bias2 = bias2; sp.wfa = wfa; sp.bfa = bfa;
    sp.sent = sent; sp.idx = idxW; sp.rank = rankW; sp.lens = lens;
    sp.D2 = D2; sp.gc = gcW;
    sp.hF0 = hA; sp.hF1 = hB; sp.cW = cWs;
    sp.hb0 = hbfA; sp.hb1 = hbfB;
    sp.outH = outH; sp.outA = outA;
    sp.barCnt = barCnt;

    void* args[] = { &sp };
    hipLaunchCooperativeKernel(reinterpret_cast<void*>(k_scan), dim3(NBLK), dim3(NTHR),
                               args, 0, stream);
}

// Round 11
// 10451.275 us; speedup vs baseline: 1.3933x; 1.0053x over previous
//
#include <hip/hip_runtime.h>
#include <hip/hip_bf16.h>
#include <math.h>

#define B 64
#define T 160
#define P 196
#define ENC 2048
#define ATT 512
#define EMB 512
#define HID 1024
#define KTOT 3584   // EMB + ENC + HID
#define N2 2560     // ATT + ENC
#define KT4 112     // KTOT/32
#define NTHR 1024
#define NBLK 256
#define NGRP 16
#define GRPSZ (NBLK/NGRP)

typedef __attribute__((ext_vector_type(8))) short bf16x8;
typedef __attribute__((ext_vector_type(4))) float f32x4;

__device__ __forceinline__ float sigm(float x){ return 1.0f/(1.0f+__expf(-x)); }
__device__ __forceinline__ float bfu(short s){ return __uint_as_float(((unsigned)(unsigned short)s) << 16); }

// ---- cache-coherent (MALL-level) data movement, no fences needed ----
__device__ __forceinline__ float ldgf(const float* p){
    return __hip_atomic_load(p, __ATOMIC_RELAXED, __HIP_MEMORY_SCOPE_AGENT);
}
__device__ __forceinline__ void stgf(float* p, float v){
    __hip_atomic_store(p, v, __ATOMIC_RELAXED, __HIP_MEMORY_SCOPE_AGENT);
}
__device__ __forceinline__ void stgu(unsigned* p, unsigned v){
    __hip_atomic_store(p, v, __ATOMIC_RELAXED, __HIP_MEMORY_SCOPE_AGENT);
}
__device__ __forceinline__ bf16x8 ldg16(const short* p){
    union { bf16x8 v; unsigned long long q[2]; } u;
    u.q[0] = __hip_atomic_load((const unsigned long long*)p,     __ATOMIC_RELAXED, __HIP_MEMORY_SCOPE_AGENT);
    u.q[1] = __hip_atomic_load((const unsigned long long*)(p+4), __ATOMIC_RELAXED, __HIP_MEMORY_SCOPE_AGENT);
    return u.v;
}
__device__ __forceinline__ unsigned pkbf(float a, float b){
    unsigned ua = (unsigned)__bfloat16_as_ushort(__float2bfloat16(a));
    unsigned ub = (unsigned)__bfloat16_as_ushort(__float2bfloat16(b));
    return ua | (ub << 16);
}

// fence-free hierarchical grid barrier: per-wave vmcnt drain, then counters.
__device__ __forceinline__ void gbar(unsigned* bar, unsigned k){
    asm volatile("s_waitcnt vmcnt(0)" ::: "memory");   // our stores (incl. agent-scope) complete
    __syncthreads();
    if (threadIdx.x == 0){
        unsigned g = blockIdx.x & (NGRP-1);
        unsigned* gcnt = bar + g*256;
        unsigned* top  = bar + NGRP*256;
        unsigned old = __hip_atomic_fetch_add(gcnt, 1u, __ATOMIC_RELAXED, __HIP_MEMORY_SCOPE_AGENT);
        if (old == (k + 1u)*GRPSZ - 1u){
            __hip_atomic_fetch_add(top, 1u, __ATOMIC_RELAXED, __HIP_MEMORY_SCOPE_AGENT);
        }
        unsigned target = (k + 1u)*NGRP;
        while (__hip_atomic_load(top, __ATOMIC_RELAXED, __HIP_MEMORY_SCOPE_AGENT) < target){
            __builtin_amdgcn_s_sleep(2);
        }
    }
    __syncthreads();
    asm volatile("" ::: "memory");                     // no compiler hoisting of loads above spin
}

// ---------- sort: stable descending by lens ----------
__global__ void k_sort(const int* lens, int* idx, int* rank, unsigned* barCnt){
    __shared__ int L[B];
    int i = threadIdx.x;
    L[i] = lens[i];
    if (i <= NGRP) barCnt[i*256] = 0u;     // 16 group counters + top
    __syncthreads();
    int li = L[i];
    int r = 0;
    for (int j = 0; j < B; ++j){
        int lj = L[j];
        if (lj > li || (lj == li && j < i)) r++;
    }
    rank[i] = r;
    idx[r] = i;
}

// ---------- init h0/c0 (sorted order) + bf16 copy ----------
__global__ void k_init_hc(const float* enc_h, const float* enc_c, const int* idx,
                          float* h, float* c, __hip_bfloat16* h_bf){
    int j = blockIdx.x;
    int o = idx[j];
    for (int k = threadIdx.x; k < HID; k += blockDim.x){
        float hv = (k < 512) ? enc_h[o*512 + k] : enc_h[B*512 + o*512 + (k-512)];
        float cv = (k < 512) ? enc_c[o*512 + k] : enc_c[B*512 + o*512 + (k-512)];
        h[j*HID + k] = hv;
        c[j*HID + k] = cv;
        h_bf[j*HID + k] = __float2bfloat16(hv);
    }
}

// ---------- Wcat in per-strip MFMA-fragment order (once) ----------
__global__ void k_cvt_wcat(const float* Wih, const float* Whh, __hip_bfloat16* Wfrag){
    size_t i = (size_t)blockIdx.x*256 + threadIdx.x;   // 57,344 blocks -> 14,680,064
    int e = (int)(i & 7);
    size_t t2 = i >> 3;
    int lane = (int)(t2 & 63);
    size_t t3 = t2 >> 6;
    int kt = (int)(t3 % KT4);
    int strip = (int)(t3 / KT4);
    int n = strip*16 + (lane & 15);
    int r = (n & 3)*HID + (n >> 2);
    int k = kt*32 + (lane >> 4)*8 + e;
    float v = (k < EMB+ENC) ? Wih[(size_t)r*(EMB+ENC) + k]
                            : Whh[(size_t)r*HID + (k - EMB - ENC)];
    Wfrag[i] = __float2bfloat16(v);
}

__global__ void k_bsum(const float* bih, const float* bhh, float* bsum){
    int n = blockIdx.x*256 + threadIdx.x;
    int r = (n & 3)*HID + (n >> 2);
    bsum[n] = bih[r] + bhh[r];
}

__global__ void k_cvt_w2(const float* Wda, const float* bda, const float* Wfb, const float* bfb,
                         __hip_bfloat16* W2, float* bias2){
    int n = blockIdx.x;              // 0..2559
    const float* src = (n < ATT) ? (Wda + (size_t)n*HID) : (Wfb + (size_t)(n-ATT)*HID);
    __hip_bfloat16* dst = W2 + (size_t)n*HID;
    for (int k = threadIdx.x; k < HID; k += 256) dst[k] = __float2bfloat16(src[k]);
    if (threadIdx.x == 0) bias2[n] = (n < ATT) ? bda[n] : bfb[n-ATT];
}

__global__ void k_cvt_emb(const float* emb, __hip_bfloat16* emb_bf){
    size_t i = (size_t)blockIdx.x*256 + threadIdx.x;
    emb_bf[i] = __float2bfloat16(emb[i]);
}

__global__ void k_cvt_wea(const float* Wea, __hip_bfloat16* Wea_bf){
    int n = blockIdx.x;
    for (int k = threadIdx.x; k < ENC; k += 256)
        Wea_bf[(size_t)n*ENC + k] = __float2bfloat16(Wea[(size_t)n*ENC + k]);
}

__global__ void k_cvt_img(const float* img, const int* idx, __hip_bfloat16* img_s){
    int j = blockIdx.y;
    int o = idx[j];
    size_t off = (size_t)blockIdx.x*256 + threadIdx.x;
    img_s[(size_t)j*P*ENC + off] = __float2bfloat16(img[(size_t)o*P*ENC + off]);
}

// ---------- att1 (once, MFMA) ----------
__global__ __launch_bounds__(256) void k_att1m(const __hip_bfloat16* img_s, const __hip_bfloat16* Wea_bf,
                                               const float* bea, __hip_bfloat16* att1w){
    int m0 = blockIdx.x * 64, n0 = blockIdx.y * 64;
    int tid = threadIdx.x, w = tid >> 6, l = tid & 63, lm = l & 15, lk = l >> 4;
    const short* ap = (const short*)img_s + (size_t)(m0 + 16*w + lm)*ENC + 8*lk;
    const short* bp = (const short*)Wea_bf + (size_t)(n0 + lm)*ENC + 8*lk;
    f32x4 acc[4];
    #pragma unroll
    for (int nt=0; nt<4; ++nt) acc[nt] = (f32x4){0.f,0.f,0.f,0.f};
    #pragma unroll 4
    for (int kt = 0; kt < ENC/32; ++kt){
        bf16x8 a = *(const bf16x8*)(ap + kt*32);
        #pragma unroll
        for (int nt=0; nt<4; ++nt){
            bf16x8 bb = *(const bf16x8*)(bp + (size_t)nt*16*ENC + kt*32);
            acc[nt] = __builtin_amdgcn_mfma_f32_16x16x32_bf16(a, bb, acc[nt], 0,0,0);
        }
    }
    #pragma unroll
    for (int nt=0; nt<4; ++nt){
        int n = n0 + nt*16 + lm;
        float bv = bea[n];
        #pragma unroll
        for (int r=0; r<4; ++r){
            int m = m0 + 16*w + 4*lk + r;
            att1w[(size_t)m*ATT + n] = __float2bfloat16(acc[nt][r] + bv);
        }
    }
}

// ---------- persistent cooperative scan ----------
struct SP {
    const __hip_bfloat16 *att1w, *img_s, *emb_bf, *Wfrag, *W2;
    const float *bsum, *bias2, *wfa, *bfa;
    const int *sent, *idx, *rank, *lens;
    float *D2;
    __hip_bfloat16 *gc;
    float *hF0, *hF1, *cW;
    __hip_bfloat16 *hb0, *hb1;
    float *outH, *outA;
    unsigned *barCnt;
};

__global__ __launch_bounds__(1024, 4) void k_scan(SP p){
    __shared__ short WcatL[KT4*64*8];          // 114,688 B, fragment-ordered
    __shared__ union {
        struct { float Dp[4][64][17]; float hS[64][4]; int tokL[64], lensL[64], wLs[64]; } gem;
        struct { float att2L[512]; float wfaL[512]; float red[1024]; float aL[208]; float ctxP[8][512]; } p23;
    } sh;

    int b = blockIdx.x, tid = threadIdx.x;
    int w = tid >> 6, l = tid & 63, lm = l & 15, lk = l >> 4;
    unsigned bk = 0;

    // one-time LDS fill (straight copy, frag order)
    {
        const bf16x8* src = (const bf16x8*)((const short*)p.Wfrag + (size_t)b*KT4*64*8);
        bf16x8* dst = (bf16x8*)WcatL;
        #pragma unroll
        for (int i = 0; i < KT4*64/NTHR; ++i) dst[tid + i*NTHR] = src[tid + i*NTHR];
    }
    __syncthreads();

    float bfa0 = p.bfa[0];

    for (int t = 0; t < T; ++t){
        const __hip_bfloat16* hbIn = (t & 1) ? p.hb1 : p.hb0;
        __hip_bfloat16*       hbOut = (t & 1) ? p.hb0 : p.hb1;
        const float* hFIn = (t & 1) ? p.hF1 : p.hF0;
        float*       hFOut = (t & 1) ? p.hF0 : p.hF1;

        // ---- P1: D2[64][2560] = h_bf @ W2^T + bias2 ; blocks < 160, 4-way K-split ----
        if (b < N2/16){
            int n0 = b*16;
            int rt = w & 3, kq = w >> 2;     // 4 row-tiles x 4 K-quarters
            const short* ap = (const short*)hbIn + (size_t)(16*rt + lm)*HID + kq*256 + 8*lk;
            const short* bp = (const short*)p.W2 + (size_t)(n0 + lm)*HID + kq*256 + 8*lk;
            f32x4 acc = {0.f,0.f,0.f,0.f};
            #pragma unroll
            for (int kt = 0; kt < 8; ++kt){
                bf16x8 a = ldg16(ap + kt*32);
                bf16x8 bb = *(const bf16x8*)(bp + kt*32);
                acc = __builtin_amdgcn_mfma_f32_16x16x32_bf16(a, bb, acc, 0,0,0);
            }
            #pragma unroll
            for (int r=0; r<4; ++r) sh.gem.Dp[kq][16*rt + 4*lk + r][lm] = acc[r];
            __syncthreads();
            int m = tid >> 4, nl = tid & 15;
            stgf(&p.D2[m*N2 + n0 + nl],
                 sh.gem.Dp[0][m][nl] + sh.gem.Dp[1][m][nl]
               + sh.gem.Dp[2][m][nl] + sh.gem.Dp[3][m][nl] + p.bias2[n0 + nl]);
        }
        gbar(p.barCnt, bk++);

        // ---- P23: e + softmax + context + gc ; block = (j=b&63, q=b>>6) ----
        {
            int j = b & 63, q = b >> 6;
            int o = p.idx[j], wj = p.rank[j], lj = p.lens[o];
            if (t < lj){
                if (tid < 512){
                    sh.p23.att2L[tid] = ldgf(&p.D2[j*N2 + tid]);
                    sh.p23.wfaL[tid]  = p.wfa[tid];
                }
                __syncthreads();

                int pp = tid & 255, ah = tid >> 8;
                float acc = 0.f;
                if (pp < P){
                    const short* ar = (const short*)p.att1w + (size_t)(j*P + pp)*ATT + ah*128;
                    #pragma unroll 8
                    for (int k8 = 0; k8 < 16; ++k8){
                        bf16x8 v = *(const bf16x8*)(ar + k8*8);
                        #pragma unroll
                        for (int z=0; z<8; ++z){
                            int a = ah*128 + k8*8 + z;
                            acc += fmaxf(bfu(v[z]) + sh.p23.att2L[a], 0.f) * sh.p23.wfaL[a];
                        }
                    }
                }
                sh.p23.red[tid] = acc;
                __syncthreads();
                float e = -1e30f;
                if (tid < P) e = sh.p23.red[tid] + sh.p23.red[tid+256] + sh.p23.red[tid+512] + sh.p23.red[tid+768] + bfa0;
                __syncthreads();
                sh.p23.red[tid] = (tid < P) ? e : -1e30f;
                __syncthreads();
                for (int s = 512; s > 0; s >>= 1){
                    if (tid < s) sh.p23.red[tid] = fmaxf(sh.p23.red[tid], sh.p23.red[tid+s]);
                    __syncthreads();
                }
                float m = sh.p23.red[0];
                __syncthreads();
                float ex = (tid < P) ? __expf(e - m) : 0.f;
                sh.p23.red[tid] = ex;
                __syncthreads();
                for (int s = 512; s > 0; s >>= 1){
                    if (tid < s) sh.p23.red[tid] += sh.p23.red[tid+s];
                    __syncthreads();
                }
                float ssum = sh.p23.red[0];
                if (tid < P){
                    float alpha = ex / ssum;
                    sh.p23.aL[tid] = alpha;
                    if (q == 0) p.outA[((size_t)(wj*T + t))*P + tid] = alpha;
                }
                if (tid >= P && tid < 208) sh.p23.aL[tid] = 0.f;
                __syncthreads();

                // context quarter [q*512, q*512+512): wave w takes p = w, w+16, ...
                const short* ib = (const short*)p.img_s + (size_t)j*P*ENC + q*512 + l*8;
                float a8[8];
                #pragma unroll
                for (int z=0; z<8; ++z) a8[z] = 0.f;
                #pragma unroll 4
                for (int i = 0; i < 13; ++i){
                    int pp2 = w + 16*i;
                    int pr = (pp2 < P) ? pp2 : 0;
                    bf16x8 v = *(const bf16x8*)(ib + (size_t)pr*ENC);
                    float al = sh.p23.aL[pp2];
                    #pragma unroll
                    for (int z=0; z<8; ++z) a8[z] += al * bfu(v[z]);
                }
                if (w < 8){
                    #pragma unroll
                    for (int z=0; z<8; ++z) sh.p23.ctxP[w][l*8+z] = a8[z];
                }
                __syncthreads();
                if (w >= 8){
                    #pragma unroll
                    for (int z=0; z<8; ++z) sh.p23.ctxP[w-8][l*8+z] += a8[z];
                }
                __syncthreads();
                if (tid < 256){
                    int d0 = 2*tid;
                    float c0 = 0.f, c1 = 0.f;
                    #pragma unroll
                    for (int r=0; r<8; ++r){ c0 += sh.p23.ctxP[r][d0]; c1 += sh.p23.ctxP[r][d0+1]; }
                    int eg0 = q*512 + d0;
                    float g0 = sigm(ldgf(&p.D2[j*N2 + ATT + eg0]));
                    float g1 = sigm(ldgf(&p.D2[j*N2 + ATT + eg0 + 1]));
                    stgu((unsigned*)((short*)p.gc + j*ENC + eg0), pkbf(g0*c0, g1*c1));
                }
            } else {
                // finished sentence: outputs are zeros; h/c held; stale gc is fine (deterministic)
                if (q == 0 && tid < P) p.outA[((size_t)(wj*T + t))*P + tid] = 0.f;
            }
        }
        gbar(p.barCnt, bk++);

        // ---- P4: gates GEMM (4-way K-split, B from LDS) + LSTM + outputs ----
        {
            if (tid < 64){
                int o = p.idx[tid];
                sh.gem.tokL[tid] = p.sent[o*T + t];
                sh.gem.lensL[tid] = p.lens[o];
                sh.gem.wLs[tid] = p.rank[tid];
            }
            __syncthreads();
            int rt = w & 3, kq = w >> 2;
            int mrow = 16*rt + lm;
            int tok = sh.gem.tokL[mrow];
            const short* aEmb = (const short*)p.emb_bf + (size_t)tok*EMB + 8*lk;
            const short* aGc  = (const short*)p.gc + (size_t)mrow*ENC + 8*lk;
            const short* aH   = (const short*)hbIn + (size_t)mrow*HID + 8*lk;
            const bf16x8* BL = (const bf16x8*)WcatL;
            f32x4 acc = {0.f,0.f,0.f,0.f};
            // K quarters of 28 kt: [0,28)=emb16+gc12, [28,56)=gc, [56,84)=gc24+h4, [84,112)=h
            if (kq == 0){
                #pragma unroll 8
                for (int kt = 0; kt < 16; ++kt){
                    bf16x8 a = *(const bf16x8*)(aEmb + kt*32);
                    acc = __builtin_amdgcn_mfma_f32_16x16x32_bf16(a, BL[kt*64 + l], acc, 0,0,0);
                }
                #pragma unroll 6
                for (int kt = 16; kt < 28; ++kt){
                    bf16x8 a = ldg16(aGc + (kt-16)*32);
                    acc = __builtin_amdgcn_mfma_f32_16x16x32_bf16(a, BL[kt*64 + l], acc, 0,0,0);
                }
            } else if (kq == 1){
                #pragma unroll 7
                for (int kt = 28; kt < 56; ++kt){
                    bf16x8 a = ldg16(aGc + (kt-16)*32);
                    acc = __builtin_amdgcn_mfma_f32_16x16x32_bf16(a, BL[kt*64 + l], acc, 0,0,0);
                }
            } else if (kq == 2){
                #pragma unroll 6
                for (int kt = 56; kt < 80; ++kt){
                    bf16x8 a = ldg16(aGc + (kt-16)*32);
                    acc = __builtin_amdgcn_mfma_f32_16x16x32_bf16(a, BL[kt*64 + l], acc, 0,0,0);
                }
                #pragma unroll
                for (int kt = 80; kt < 84; ++kt){
                    bf16x8 a = ldg16(aH + (kt-80)*32);
                    acc = __builtin_amdgcn_mfma_f32_16x16x32_bf16(a, BL[kt*64 + l], acc, 0,0,0);
                }
            } else {
                #pragma unroll 7
                for (int kt = 84; kt < 112; ++kt){
                    bf16x8 a = ldg16(aH + (kt-80)*32);
                    acc = __builtin_amdgcn_mfma_f32_16x16x32_bf16(a, BL[kt*64 + l], acc, 0,0,0);
                }
            }
            #pragma unroll
            for (int r=0; r<4; ++r) sh.gem.Dp[kq][16*rt + 4*lk + r][lm] = acc[r];
            __syncthreads();
            if (tid < 256){
                int j2 = tid & 63, du = tid >> 6;
                int u = 4*b + du;
                float g4[4];
                #pragma unroll
                for (int g=0; g<4; ++g){
                    int nl = 4*du + g;
                    g4[g] = sh.gem.Dp[0][j2][nl] + sh.gem.Dp[1][j2][nl]
                          + sh.gem.Dp[2][j2][nl] + sh.gem.Dp[3][j2][nl] + p.bsum[16*b + nl];
                }
                float ig = sigm(g4[0]), fg = sigm(g4[1]), gg = tanhf(g4[2]), og = sigm(g4[3]);
                float cOld = p.cW[j2*HID + u];
                float cNew = fg*cOld + ig*gg;
                float hNew = og*tanhf(cNew);
                bool active = (t < sh.gem.lensL[j2]);
                float hOld = hFIn[j2*HID + u];
                float hKeep = active ? hNew : hOld;
                hFOut[j2*HID + u] = hKeep;
                sh.gem.hS[j2][du] = hKeep;
                p.cW[j2*HID + u] = active ? cNew : cOld;
                p.outH[((size_t)sh.gem.wLs[j2]*T + t)*HID + u] = active ? hNew : 0.f;
            }
            __syncthreads();
            if (tid < 128){
                int j2 = tid & 63, dp = tid >> 6;    // dp in {0,1}
                int u0 = 4*b + 2*dp;
                stgu((unsigned*)((short*)hbOut + j2*HID + u0),
                     pkbf(sh.gem.hS[j2][2*dp], sh.gem.hS[j2][2*dp+1]));
            }
        }
        gbar(p.barCnt, bk++);
    }
}

extern "C" void kernel_launch(void* const* d_in, const int* in_sizes, int n_in,
                              void* d_out, int out_size, void* d_ws, size_t ws_size,
                              hipStream_t stream) {
    const float* img   = (const float*)d_in[0];
    const int*   sent  = (const int*)  d_in[1];
    const float* enc_h = (const float*)d_in[2];
    const float* enc_c = (const float*)d_in[3];
    const int*   lens  = (const int*)  d_in[4];
    const float* emb   = (const float*)d_in[5];
    const float* Wea   = (const float*)d_in[6];
    const float* bea   = (const float*)d_in[7];
    const float* Wda   = (const float*)d_in[8];
    const float* bda   = (const float*)d_in[9];
    const float* wfa   = (const float*)d_in[10];
    const float* bfa   = (const float*)d_in[11];
    const float* Wfb   = (const float*)d_in[12];
    const float* bfb   = (const float*)d_in[13];
    const float* Wih   = (const float*)d_in[14];
    const float* bih   = (const float*)d_in[15];
    const float* Whh   = (const float*)d_in[16];
    const float* bhh   = (const float*)d_in[17];

    float* outH = (float*)d_out;                       // [B,T,HID] f32
    float* outA = outH + (size_t)B*T*HID;              // [B,T,P]  f32

    char* wsb = (char*)d_ws;
    size_t off = 0;
    int* idxW  = (int*)(wsb + off); off += 256;
    int* rankW = (int*)(wsb + off); off += 256;
    unsigned* barCnt = (unsigned*)(wsb + off); off += 32768;   // 16 group counters (1KB apart) + top
    __hip_bfloat16* att1w = (__hip_bfloat16*)(wsb + off); off += (size_t)B*P*ATT*2;       // 12.85MB
    __hip_bfloat16* img_s = (__hip_bfloat16*)(wsb + off); off += (size_t)B*P*ENC*2;       // 51.38MB
    __hip_bfloat16* emb_bf= (__hip_bfloat16*)(wsb + off); off += (size_t)10000*EMB*2;     // 10.24MB
    __hip_bfloat16* Wfrag = (__hip_bfloat16*)(wsb + off); off += (size_t)4*HID*KTOT*2;    // 29.36MB
    __hip_bfloat16* W2    = (__hip_bfloat16*)(wsb + off); off += (size_t)N2*HID*2;        // 5.24MB
    __hip_bfloat16* Wea_bf= (__hip_bfloat16*)(wsb + off); off += (size_t)ATT*ENC*2;       // 2.10MB (prologue-only)
    float* bsum  = (float*)(wsb + off); off += 4*HID*4;
    float* bias2 = (float*)(wsb + off); off += N2*4;
    float* hA    = (float*)(wsb + off); off += B*HID*4;
    float* hB    = (float*)(wsb + off); off += B*HID*4;
    float* cWs   = (float*)(wsb + off); off += B*HID*4;
    __hip_bfloat16* hbfA = (__hip_bfloat16*)(wsb + off); off += B*HID*2;
    __hip_bfloat16* hbfB = (__hip_bfloat16*)(wsb + off); off += B*HID*2;
    float* D2    = (float*)(wsb + off); off += (size_t)B*N2*4;
    __hip_bfloat16* gcW  = (__hip_bfloat16*)(wsb + off); off += B*ENC*2;

    k_sort<<<1, 64, 0, stream>>>(lens, idxW, rankW, barCnt);
    k_init_hc<<<B, 256, 0, stream>>>(enc_h, enc_c, idxW, hA, cWs, hbfA);
    k_cvt_wcat<<<57344, 256, 0, stream>>>(Wih, Whh, Wfrag);
    k_bsum<<<16, 256, 0, stream>>>(bih, bhh, bsum);
    k_cvt_w2<<<N2, 256, 0, stream>>>(Wda, bda, Wfb, bfb, W2, bias2);
    k_cvt_emb<<<20000, 256, 0, stream>>>(emb, emb_bf);
    k_cvt_wea<<<ATT, 256, 0, stream>>>(Wea, Wea_bf);
    k_cvt_img<<<dim3(P*ENC/256, B), 256, 0, stream>>>(img, idxW, img_s);
    k_att1m<<<dim3((B*P)/64, ATT/64), 256, 0, stream>>>(img_s, Wea_bf, bea, att1w);

    SP sp;
    sp.att1w = att1w; sp.img_s = img_s; sp.emb_bf = emb_bf; sp.Wfrag = Wfrag; sp.W2 = W2;
    sp.bsum = bsum; sp.bias2 = bias2; sp.wfa = wfa; sp.bfa = bfa;
    sp.sent = sent; sp.idx = idxW; sp.rank = rankW; sp.lens = lens;
    sp.D2 = D2; sp.gc = gcW;
    sp.hF0 = hA; sp.hF1 = hB; sp.cW = cWs;
    sp.hb0 = hbfA; sp.hb1 = hbfB;
    sp.outH = outH; sp.outA = outA;
    sp.barCnt = barCnt;

    void* args[] = { &sp };
    hipLaunchCooperativeKernel(reinterpret_cast<void*>(k_scan), dim3(NBLK), dim3(NTHR),
                               args, 0, stream);
}

// Round 12
// 8365.298 us; speedup vs baseline: 1.7407x; 1.2494x over previous
//
#include <hip/hip_runtime.h>
#include <hip/hip_bf16.h>
#include <math.h>

#define B 64
#define T 160
#define P 196
#define ENC 2048
#define ATT 512
#define EMB 512
#define HID 1024
#define KTOT 3584   // EMB + ENC + HID
#define N2 2560     // ATT + ENC
#define KT4 112     // KTOT/32
#define NTHR 1024
#define NBLK 256
#define NGRP 16
#define GRPSZ (NBLK/NGRP)

typedef __attribute__((ext_vector_type(8))) short bf16x8;
typedef __attribute__((ext_vector_type(4))) float f32x4;
typedef float __attribute__((ext_vector_type(4))) vf4;

__device__ __forceinline__ float sigm(float x){ return 1.0f/(1.0f+__expf(-x)); }
__device__ __forceinline__ float bfu(short s){ return __uint_as_float(((unsigned)(unsigned short)s) << 16); }

// ---- MALL-coherent data movement via volatile (sc0 sc1) wide loads/stores ----
// gfx940+: volatile lowers to sc0=1 sc1=1 (bypass L1/L2, coherent at MALL) on the
// normal pipelined vector-memory path (vs the throttled TCC atomic path).
__device__ __forceinline__ float ldgf(const float* p){
    return *(const volatile float*)p;
}
__device__ __forceinline__ void stgf(float* p, float v){
    *(volatile float*)p = v;
}
__device__ __forceinline__ void stgu(unsigned* p, unsigned v){
    *(volatile unsigned*)p = v;
}
__device__ __forceinline__ bf16x8 ldg16(const short* p){
    union { vf4 f; bf16x8 v; } u;
    u.f = *(const volatile vf4*)p;     // single global_load_dwordx4 sc0 sc1
    return u.v;
}
__device__ __forceinline__ unsigned pkbf(float a, float b){
    unsigned ua = (unsigned)__bfloat16_as_ushort(__float2bfloat16(a));
    unsigned ub = (unsigned)__bfloat16_as_ushort(__float2bfloat16(b));
    return ua | (ub << 16);
}

// fence-free hierarchical grid barrier: per-wave vmcnt drain, then counters.
__device__ __forceinline__ void gbar(unsigned* bar, unsigned k){
    asm volatile("s_waitcnt vmcnt(0)" ::: "memory");   // our volatile stores complete
    __syncthreads();
    if (threadIdx.x == 0){
        unsigned g = blockIdx.x & (NGRP-1);
        unsigned* gcnt = bar + g*256;
        unsigned* top  = bar + NGRP*256;
        unsigned old = __hip_atomic_fetch_add(gcnt, 1u, __ATOMIC_RELAXED, __HIP_MEMORY_SCOPE_AGENT);
        if (old == (k + 1u)*GRPSZ - 1u){
            __hip_atomic_fetch_add(top, 1u, __ATOMIC_RELAXED, __HIP_MEMORY_SCOPE_AGENT);
        }
        unsigned target = (k + 1u)*NGRP;
        while (__hip_atomic_load(top, __ATOMIC_RELAXED, __HIP_MEMORY_SCOPE_AGENT) < target){
            __builtin_amdgcn_s_sleep(2);
        }
    }
    __syncthreads();
    asm volatile("" ::: "memory");                     // no compiler hoisting of loads above spin
}

// ---------- sort: stable descending by lens ----------
__global__ void k_sort(const int* lens, int* idx, int* rank, unsigned* barCnt){
    __shared__ int L[B];
    int i = threadIdx.x;
    L[i] = lens[i];
    if (i <= NGRP) barCnt[i*256] = 0u;     // 16 group counters + top
    __syncthreads();
    int li = L[i];
    int r = 0;
    for (int j = 0; j < B; ++j){
        int lj = L[j];
        if (lj > li || (lj == li && j < i)) r++;
    }
    rank[i] = r;
    idx[r] = i;
}

// ---------- init h0/c0 (sorted order) + bf16 copy ----------
__global__ void k_init_hc(const float* enc_h, const float* enc_c, const int* idx,
                          float* h, float* c, __hip_bfloat16* h_bf){
    int j = blockIdx.x;
    int o = idx[j];
    for (int k = threadIdx.x; k < HID; k += blockDim.x){
        float hv = (k < 512) ? enc_h[o*512 + k] : enc_h[B*512 + o*512 + (k-512)];
        float cv = (k < 512) ? enc_c[o*512 + k] : enc_c[B*512 + o*512 + (k-512)];
        h[j*HID + k] = hv;
        c[j*HID + k] = cv;
        h_bf[j*HID + k] = __float2bfloat16(hv);
    }
}

// ---------- Wcat in per-strip MFMA-fragment order (once) ----------
__global__ void k_cvt_wcat(const float* Wih, const float* Whh, __hip_bfloat16* Wfrag){
    size_t i = (size_t)blockIdx.x*256 + threadIdx.x;   // 57,344 blocks -> 14,680,064
    int e = (int)(i & 7);
    size_t t2 = i >> 3;
    int lane = (int)(t2 & 63);
    size_t t3 = t2 >> 6;
    int kt = (int)(t3 % KT4);
    int strip = (int)(t3 / KT4);
    int n = strip*16 + (lane & 15);
    int r = (n & 3)*HID + (n >> 2);
    int k = kt*32 + (lane >> 4)*8 + e;
    float v = (k < EMB+ENC) ? Wih[(size_t)r*(EMB+ENC) + k]
                            : Whh[(size_t)r*HID + (k - EMB - ENC)];
    Wfrag[i] = __float2bfloat16(v);
}

__global__ void k_bsum(const float* bih, const float* bhh, float* bsum){
    int n = blockIdx.x*256 + threadIdx.x;
    int r = (n & 3)*HID + (n >> 2);
    bsum[n] = bih[r] + bhh[r];
}

__global__ void k_cvt_w2(const float* Wda, const float* bda, const float* Wfb, const float* bfb,
                         __hip_bfloat16* W2, float* bias2){
    int n = blockIdx.x;              // 0..2559
    const float* src = (n < ATT) ? (Wda + (size_t)n*HID) : (Wfb + (size_t)(n-ATT)*HID);
    __hip_bfloat16* dst = W2 + (size_t)n*HID;
    for (int k = threadIdx.x; k < HID; k += 256) dst[k] = __float2bfloat16(src[k]);
    if (threadIdx.x == 0) bias2[n] = (n < ATT) ? bda[n] : bfb[n-ATT];
}

__global__ void k_cvt_emb(const float* emb, __hip_bfloat16* emb_bf){
    size_t i = (size_t)blockIdx.x*256 + threadIdx.x;
    emb_bf[i] = __float2bfloat16(emb[i]);
}

__global__ void k_cvt_wea(const float* Wea, __hip_bfloat16* Wea_bf){
    int n = blockIdx.x;
    for (int k = threadIdx.x; k < ENC; k += 256)
        Wea_bf[(size_t)n*ENC + k] = __float2bfloat16(Wea[(size_t)n*ENC + k]);
}

__global__ void k_cvt_img(const float* img, const int* idx, __hip_bfloat16* img_s){
    int j = blockIdx.y;
    int o = idx[j];
    size_t off = (size_t)blockIdx.x*256 + threadIdx.x;
    img_s[(size_t)j*P*ENC + off] = __float2bfloat16(img[(size_t)o*P*ENC + off]);
}

// ---------- att1 (once, MFMA) ----------
__global__ __launch_bounds__(256) void k_att1m(const __hip_bfloat16* img_s, const __hip_bfloat16* Wea_bf,
                                               const float* bea, __hip_bfloat16* att1w){
    int m0 = blockIdx.x * 64, n0 = blockIdx.y * 64;
    int tid = threadIdx.x, w = tid >> 6, l = tid & 63, lm = l & 15, lk = l >> 4;
    const short* ap = (const short*)img_s + (size_t)(m0 + 16*w + lm)*ENC + 8*lk;
    const short* bp = (const short*)Wea_bf + (size_t)(n0 + lm)*ENC + 8*lk;
    f32x4 acc[4];
    #pragma unroll
    for (int nt=0; nt<4; ++nt) acc[nt] = (f32x4){0.f,0.f,0.f,0.f};
    #pragma unroll 4
    for (int kt = 0; kt < ENC/32; ++kt){
        bf16x8 a = *(const bf16x8*)(ap + kt*32);
        #pragma unroll
        for (int nt=0; nt<4; ++nt){
            bf16x8 bb = *(const bf16x8*)(bp + (size_t)nt*16*ENC + kt*32);
            acc[nt] = __builtin_amdgcn_mfma_f32_16x16x32_bf16(a, bb, acc[nt], 0,0,0);
        }
    }
    #pragma unroll
    for (int nt=0; nt<4; ++nt){
        int n = n0 + nt*16 + lm;
        float bv = bea[n];
        #pragma unroll
        for (int r=0; r<4; ++r){
            int m = m0 + 16*w + 4*lk + r;
            att1w[(size_t)m*ATT + n] = __float2bfloat16(acc[nt][r] + bv);
        }
    }
}

// ---------- persistent cooperative scan ----------
struct SP {
    const __hip_bfloat16 *att1w, *img_s, *emb_bf, *Wfrag, *W2;
    const float *bsum, *bias2, *wfa, *bfa;
    const int *sent, *idx, *rank, *lens;
    float *D2;
    __hip_bfloat16 *gc;
    float *hF0, *hF1, *cW;
    __hip_bfloat16 *hb0, *hb1;
    float *outH, *outA;
    unsigned *barCnt;
};

__global__ __launch_bounds__(1024, 4) void k_scan(SP p){
    __shared__ short WcatL[KT4*64*8];          // 114,688 B, fragment-ordered
    __shared__ union {
        struct { float Dp[4][64][17]; float hS[64][4]; int tokL[64], lensL[64], wLs[64]; } gem;
        struct { float att2L[512]; float wfaL[512]; float red[1024]; float aL[208]; float ctxP[8][512]; } p23;
    } sh;

    int b = blockIdx.x, tid = threadIdx.x;
    int w = tid >> 6, l = tid & 63, lm = l & 15, lk = l >> 4;
    unsigned bk = 0;

    // one-time LDS fill (straight copy, frag order)
    {
        const bf16x8* src = (const bf16x8*)((const short*)p.Wfrag + (size_t)b*KT4*64*8);
        bf16x8* dst = (bf16x8*)WcatL;
        #pragma unroll
        for (int i = 0; i < KT4*64/NTHR; ++i) dst[tid + i*NTHR] = src[tid + i*NTHR];
    }
    __syncthreads();

    float bfa0 = p.bfa[0];

    for (int t = 0; t < T; ++t){
        const __hip_bfloat16* hbIn = (t & 1) ? p.hb1 : p.hb0;
        __hip_bfloat16*       hbOut = (t & 1) ? p.hb0 : p.hb1;
        const float* hFIn = (t & 1) ? p.hF1 : p.hF0;
        float*       hFOut = (t & 1) ? p.hF0 : p.hF1;

        // ---- P1: D2[64][2560] = h_bf @ W2^T + bias2 ; blocks < 160, 4-way K-split ----
        if (b < N2/16){
            int n0 = b*16;
            int rt = w & 3, kq = w >> 2;     // 4 row-tiles x 4 K-quarters
            const short* ap = (const short*)hbIn + (size_t)(16*rt + lm)*HID + kq*256 + 8*lk;
            const short* bp = (const short*)p.W2 + (size_t)(n0 + lm)*HID + kq*256 + 8*lk;
            f32x4 acc = {0.f,0.f,0.f,0.f};
            #pragma unroll
            for (int kt = 0; kt < 8; ++kt){
                bf16x8 a = ldg16(ap + kt*32);
                bf16x8 bb = *(const bf16x8*)(bp + kt*32);
                acc = __builtin_amdgcn_mfma_f32_16x16x32_bf16(a, bb, acc, 0,0,0);
            }
            #pragma unroll
            for (int r=0; r<4; ++r) sh.gem.Dp[kq][16*rt + 4*lk + r][lm] = acc[r];
            __syncthreads();
            int m = tid >> 4, nl = tid & 15;
            stgf(&p.D2[m*N2 + n0 + nl],
                 sh.gem.Dp[0][m][nl] + sh.gem.Dp[1][m][nl]
               + sh.gem.Dp[2][m][nl] + sh.gem.Dp[3][m][nl] + p.bias2[n0 + nl]);
        }
        gbar(p.barCnt, bk++);

        // ---- P23: e + softmax + context + gc ; block = (j=b&63, q=b>>6) ----
        {
            int j = b & 63, q = b >> 6;
            int o = p.idx[j], wj = p.rank[j], lj = p.lens[o];
            if (t < lj){
                if (tid < 512){
                    sh.p23.att2L[tid] = ldgf(&p.D2[j*N2 + tid]);
                    sh.p23.wfaL[tid]  = p.wfa[tid];
                }
                __syncthreads();

                int pp = tid & 255, ah = tid >> 8;
                float acc = 0.f;
                if (pp < P){
                    const short* ar = (const short*)p.att1w + (size_t)(j*P + pp)*ATT + ah*128;
                    #pragma unroll 8
                    for (int k8 = 0; k8 < 16; ++k8){
                        bf16x8 v = *(const bf16x8*)(ar + k8*8);
                        #pragma unroll
                        for (int z=0; z<8; ++z){
                            int a = ah*128 + k8*8 + z;
                            acc += fmaxf(bfu(v[z]) + sh.p23.att2L[a], 0.f) * sh.p23.wfaL[a];
                        }
                    }
                }
                sh.p23.red[tid] = acc;
                __syncthreads();
                float e = -1e30f;
                if (tid < P) e = sh.p23.red[tid] + sh.p23.red[tid+256] + sh.p23.red[tid+512] + sh.p23.red[tid+768] + bfa0;
                __syncthreads();
                sh.p23.red[tid] = (tid < P) ? e : -1e30f;
                __syncthreads();
                for (int s = 512; s > 0; s >>= 1){
                    if (tid < s) sh.p23.red[tid] = fmaxf(sh.p23.red[tid], sh.p23.red[tid+s]);
                    __syncthreads();
                }
                float m = sh.p23.red[0];
                __syncthreads();
                float ex = (tid < P) ? __expf(e - m) : 0.f;
                sh.p23.red[tid] = ex;
                __syncthreads();
                for (int s = 512; s > 0; s >>= 1){
                    if (tid < s) sh.p23.red[tid] += sh.p23.red[tid+s];
                    __syncthreads();
                }
                float ssum = sh.p23.red[0];
                if (tid < P){
                    float alpha = ex / ssum;
                    sh.p23.aL[tid] = alpha;
                    if (q == 0) p.outA[((size_t)(wj*T + t))*P + tid] = alpha;
                }
                if (tid >= P && tid < 208) sh.p23.aL[tid] = 0.f;
                __syncthreads();

                // context quarter [q*512, q*512+512): wave w takes p = w, w+16, ...
                const short* ib = (const short*)p.img_s + (size_t)j*P*ENC + q*512 + l*8;
                float a8[8];
                #pragma unroll
                for (int z=0; z<8; ++z) a8[z] = 0.f;
                #pragma unroll 4
                for (int i = 0; i < 13; ++i){
                    int pp2 = w + 16*i;
                    int pr = (pp2 < P) ? pp2 : 0;
                    bf16x8 v = *(const bf16x8*)(ib + (size_t)pr*ENC);
                    float al = sh.p23.aL[pp2];
                    #pragma unroll
                    for (int z=0; z<8; ++z) a8[z] += al * bfu(v[z]);
                }
                if (w < 8){
                    #pragma unroll
                    for (int z=0; z<8; ++z) sh.p23.ctxP[w][l*8+z] = a8[z];
                }
                __syncthreads();
                if (w >= 8){
                    #pragma unroll
                    for (int z=0; z<8; ++z) sh.p23.ctxP[w-8][l*8+z] += a8[z];
                }
                __syncthreads();
                if (tid < 256){
                    int d0 = 2*tid;
                    float c0 = 0.f, c1 = 0.f;
                    #pragma unroll
                    for (int r=0; r<8; ++r){ c0 += sh.p23.ctxP[r][d0]; c1 += sh.p23.ctxP[r][d0+1]; }
                    int eg0 = q*512 + d0;
                    float g0 = sigm(ldgf(&p.D2[j*N2 + ATT + eg0]));
                    float g1 = sigm(ldgf(&p.D2[j*N2 + ATT + eg0 + 1]));
                    stgu((unsigned*)((short*)p.gc + j*ENC + eg0), pkbf(g0*c0, g1*c1));
                }
            } else {
                // finished sentence: outputs are zeros; h/c held; stale gc is fine (deterministic)
                if (q == 0 && tid < P) p.outA[((size_t)(wj*T + t))*P + tid] = 0.f;
            }
        }
        gbar(p.barCnt, bk++);

        // ---- P4: gates GEMM (4-way K-split, B from LDS) + LSTM + outputs ----
        {
            if (tid < 64){
                int o = p.idx[tid];
                sh.gem.tokL[tid] = p.sent[o*T + t];
                sh.gem.lensL[tid] = p.lens[o];
                sh.gem.wLs[tid] = p.rank[tid];
            }
            __syncthreads();
            int rt = w & 3, kq = w >> 2;
            int mrow = 16*rt + lm;
            int tok = sh.gem.tokL[mrow];
            const short* aEmb = (const short*)p.emb_bf + (size_t)tok*EMB + 8*lk;
            const short* aGc  = (const short*)p.gc + (size_t)mrow*ENC + 8*lk;
            const short* aH   = (const short*)hbIn + (size_t)mrow*HID + 8*lk;
            const bf16x8* BL = (const bf16x8*)WcatL;
            f32x4 acc = {0.f,0.f,0.f,0.f};
            // K quarters of 28 kt: [0,28)=emb16+gc12, [28,56)=gc, [56,84)=gc24+h4, [84,112)=h
            if (kq == 0){
                #pragma unroll 8
                for (int kt = 0; kt < 16; ++kt){
                    bf16x8 a = *(const bf16x8*)(aEmb + kt*32);
                    acc = __builtin_amdgcn_mfma_f32_16x16x32_bf16(a, BL[kt*64 + l], acc, 0,0,0);
                }
                #pragma unroll 6
                for (int kt = 16; kt < 28; ++kt){
                    bf16x8 a = ldg16(aGc + (kt-16)*32);
                    acc = __builtin_amdgcn_mfma_f32_16x16x32_bf16(a, BL[kt*64 + l], acc, 0,0,0);
                }
            } else if (kq == 1){
                #pragma unroll 7
                for (int kt = 28; kt < 56; ++kt){
                    bf16x8 a = ldg16(aGc + (kt-16)*32);
                    acc = __builtin_amdgcn_mfma_f32_16x16x32_bf16(a, BL[kt*64 + l], acc, 0,0,0);
                }
            } else if (kq == 2){
                #pragma unroll 6
                for (int kt = 56; kt < 80; ++kt){
                    bf16x8 a = ldg16(aGc + (kt-16)*32);
                    acc = __builtin_amdgcn_mfma_f32_16x16x32_bf16(a, BL[kt*64 + l], acc, 0,0,0);
                }
                #pragma unroll
                for (int kt = 80; kt < 84; ++kt){
                    bf16x8 a = ldg16(aH + (kt-80)*32);
                    acc = __builtin_amdgcn_mfma_f32_16x16x32_bf16(a, BL[kt*64 + l], acc, 0,0,0);
                }
            } else {
                #pragma unroll 7
                for (int kt = 84; kt < 112; ++kt){
                    bf16x8 a = ldg16(aH + (kt-80)*32);
                    acc = __builtin_amdgcn_mfma_f32_16x16x32_bf16(a, BL[kt*64 + l], acc, 0,0,0);
                }
            }
            #pragma unroll
            for (int r=0; r<4; ++r) sh.gem.Dp[kq][16*rt + 4*lk + r][lm] = acc[r];
            __syncthreads();
            if (tid < 256){
                int j2 = tid & 63, du = tid >> 6;
                int u = 4*b + du;
                float g4[4];
                #pragma unroll
                for (int g=0; g<4; ++g){
                    int nl = 4*du + g;
                    g4[g] = sh.gem.Dp[0][j2][nl] + sh.gem.Dp[1][j2][nl]
                          + sh.gem.Dp[2][j2][nl] + sh.gem.Dp[3][j2][nl] + p.bsum[16*b + nl];
                }
                float ig = sigm(g4[0]), fg = sigm(g4[1]), gg = tanhf(g4[2]), og = sigm(g4[3]);
                float cOld = p.cW[j2*HID + u];
                float cNew = fg*cOld + ig*gg;
                float hNew = og*tanhf(cNew);
                bool active = (t < sh.gem.lensL[j2]);
                float hOld = hFIn[j2*HID + u];
                float hKeep = active ? hNew : hOld;
                hFOut[j2*HID + u] = hKeep;
                sh.gem.hS[j2][du] = hKeep;
                p.cW[j2*HID + u] = active ? cNew : cOld;
                p.outH[((size_t)sh.gem.wLs[j2]*T + t)*HID + u] = active ? hNew : 0.f;
            }
            __syncthreads();
            if (tid < 128){
                int j2 = tid & 63, dp = tid >> 6;    // dp in {0,1}
                int u0 = 4*b + 2*dp;
                stgu((unsigned*)((short*)hbOut + j2*HID + u0),
                     pkbf(sh.gem.hS[j2][2*dp], sh.gem.hS[j2][2*dp+1]));
            }
        }
        gbar(p.barCnt, bk++);
    }
}

extern "C" void kernel_launch(void* const* d_in, const int* in_sizes, int n_in,
                              void* d_out, int out_size, void* d_ws, size_t ws_size,
                              hipStream_t stream) {
    const float* img   = (const float*)d_in[0];
    const int*   sent  = (const int*)  d_in[1];
    const float* enc_h = (const float*)d_in[2];
    const float* enc_c = (const float*)d_in[3];
    const int*   lens  = (const int*)  d_in[4];
    const float* emb   = (const float*)d_in[5];
    const float* Wea   = (const float*)d_in[6];
    const float* bea   = (const float*)d_in[7];
    const float* Wda   = (const float*)d_in[8];
    const float* bda   = (const float*)d_in[9];
    const float* wfa   = (const float*)d_in[10];
    const float* bfa   = (const float*)d_in[11];
    const float* Wfb   = (const float*)d_in[12];
    const float* bfb   = (const float*)d_in[13];
    const float* Wih   = (const float*)d_in[14];
    const float* bih   = (const float*)d_in[15];
    const float* Whh   = (const float*)d_in[16];
    const float* bhh   = (const float*)d_in[17];

    float* outH = (float*)d_out;                       // [B,T,HID] f32
    float* outA = outH + (size_t)B*T*HID;              // [B,T,P]  f32

    char* wsb = (char*)d_ws;
    size_t off = 0;
    int* idxW  = (int*)(wsb + off); off += 256;
    int* rankW = (int*)(wsb + off); off += 256;
    unsigned* barCnt = (unsigned*)(wsb + off); off += 32768;   // 16 group counters (1KB apart) + top
    __hip_bfloat16* att1w = (__hip_bfloat16*)(wsb + off); off += (size_t)B*P*ATT*2;       // 12.85MB
    __hip_bfloat16* img_s = (__hip_bfloat16*)(wsb + off); off += (size_t)B*P*ENC*2;       // 51.38MB
    __hip_bfloat16* emb_bf= (__hip_bfloat16*)(wsb + off); off += (size_t)10000*EMB*2;     // 10.24MB
    __hip_bfloat16* Wfrag = (__hip_bfloat16*)(wsb + off); off += (size_t)4*HID*KTOT*2;    // 29.36MB
    __hip_bfloat16* W2    = (__hip_bfloat16*)(wsb + off); off += (size_t)N2*HID*2;        // 5.24MB
    __hip_bfloat16* Wea_bf= (__hip_bfloat16*)(wsb + off); off += (size_t)ATT*ENC*2;       // 2.10MB (prologue-only)
    float* bsum  = (float*)(wsb + off); off += 4*HID*4;
    float* bias2 = (float*)(wsb + off); off += N2*4;
    float* hA    = (float*)(wsb + off); off += B*HID*4;
    float* hB    = (float*)(wsb + off); off += B*HID*4;
    float* cWs   = (float*)(wsb + off); off += B*HID*4;
    __hip_bfloat16* hbfA = (__hip_bfloat16*)(wsb + off); off += B*HID*2;
    __hip_bfloat16* hbfB = (__hip_bfloat16*)(wsb + off); off += B*HID*2;
    float* D2    = (float*)(wsb + off); off += (size_t)B*N2*4;
    __hip_bfloat16* gcW  = (__hip_bfloat16*)(wsb + off); off += B*ENC*2;

    k_sort<<<1, 64, 0, stream>>>(lens, idxW, rankW, barCnt);
    k_init_hc<<<B, 256, 0, stream>>>(enc_h, enc_c, idxW, hA, cWs, hbfA);
    k_cvt_wcat<<<57344, 256, 0, stream>>>(Wih, Whh, Wfrag);
    k_bsum<<<16, 256, 0, stream>>>(bih, bhh, bsum);
    k_cvt_w2<<<N2, 256, 0, stream>>>(Wda, bda, Wfb, bfb, W2, bias2);
    k_cvt_emb<<<20000, 256, 0, stream>>>(emb, emb_bf);
    k_cvt_wea<<<ATT, 256, 0, stream>>>(Wea, Wea_bf);
    k_cvt_img<<<dim3(P*ENC/256, B), 256, 0, stream>>>(img, idxW, img_s);
    k_att1m<<<dim3((B*P)/64, ATT/64), 256, 0, stream>>>(img_s, Wea_bf, bea, att1w);

    SP sp;
    sp.att1w = att1w; sp.img_s = img_s; sp.emb_bf = emb_bf; sp.Wfrag = Wfrag; sp.W2 = W2;
    sp.bsum = bsum; sp.bias2 = bias2; sp.wfa = wfa; sp.bfa = bfa;
    sp.sent = sent; sp.idx = idxW; sp.rank = rankW; sp.lens = lens;
    sp.D2 = D2; sp.gc = gcW;
    sp.hF0 = hA; sp.hF1 = hB; sp.cW = cWs;
    sp.hb0 = hbfA; sp.hb1 = hbfB;
    sp.outH = outH; sp.outA = outA;
    sp.barCnt = barCnt;

    void* args[] = { &sp };
    hipLaunchCooperativeKernel(reinterpret_cast<void*>(k_scan), dim3(NBLK), dim3(NTHR),
                               args, 0, stream);
}

// Round 13
// 7452.119 us; speedup vs baseline: 1.9541x; 1.1225x over previous
//
#include <hip/hip_runtime.h>
#include <hip/hip_bf16.h>
#include <math.h>

#define B 64
#define T 160
#define P 196
#define ENC 2048
#define ATT 512
#define EMB 512
#define HID 1024
#define KTOT 3584   // EMB + ENC + HID
#define N2 2560     // ATT + ENC
#define KT4 112     // KTOT/32
#define NTHR 1024
#define NBLK 256
#define NGRP 16
#define GRPSZ (NBLK/NGRP)

typedef __attribute__((ext_vector_type(8))) short bf16x8;
typedef __attribute__((ext_vector_type(4))) float f32x4;
typedef float __attribute__((ext_vector_type(4))) vf4;

__device__ __forceinline__ float sigm(float x){ return 1.0f/(1.0f+__expf(-x)); }
__device__ __forceinline__ float bfu(short s){ return __uint_as_float(((unsigned)(unsigned short)s) << 16); }

// ---- MALL-coherent movement for cross-block data (volatile => sc0 sc1) ----
__device__ __forceinline__ float ldgf(const float* p){ return *(const volatile float*)p; }
__device__ __forceinline__ void stgf(float* p, float v){ *(volatile float*)p = v; }
__device__ __forceinline__ void stgu(unsigned* p, unsigned v){ *(volatile unsigned*)p = v; }
__device__ __forceinline__ unsigned pkbf(float a, float b){
    unsigned ua = (unsigned)__bfloat16_as_ushort(__float2bfloat16(a));
    unsigned ub = (unsigned)__bfloat16_as_ushort(__float2bfloat16(b));
    return ua | (ub << 16);
}

// fence-free hierarchical grid barrier (16 groups + top), volatile spin.
__device__ __forceinline__ void gbar(unsigned* bar, unsigned k){
    asm volatile("s_waitcnt vmcnt(0)" ::: "memory");
    __syncthreads();
    if (threadIdx.x == 0){
        unsigned g = blockIdx.x & (NGRP-1);
        unsigned* gcnt = bar + g*256;
        unsigned* top  = bar + NGRP*256;
        unsigned old = __hip_atomic_fetch_add(gcnt, 1u, __ATOMIC_RELAXED, __HIP_MEMORY_SCOPE_AGENT);
        if (old == (k + 1u)*GRPSZ - 1u){
            __hip_atomic_fetch_add(top, 1u, __ATOMIC_RELAXED, __HIP_MEMORY_SCOPE_AGENT);
        }
        unsigned target = (k + 1u)*NGRP;
        while (*(volatile unsigned*)top < target){
            __builtin_amdgcn_s_sleep(1);
        }
    }
    __syncthreads();
    asm volatile("" ::: "memory");
}

// ---------- sort + nAct table ----------
__global__ void k_sort(const int* lens, int* idx, int* rank, unsigned* barCnt, int* nAct){
    __shared__ int L[B];
    int i = threadIdx.x;
    L[i] = lens[i];
    if (i <= NGRP) barCnt[i*256] = 0u;
    __syncthreads();
    int li = L[i];
    int r = 0;
    for (int j = 0; j < B; ++j){
        int lj = L[j];
        if (lj > li || (lj == li && j < i)) r++;
    }
    rank[i] = r;
    idx[r] = i;
    for (int tt = i; tt < T; tt += B){
        int c = 0;
        for (int j = 0; j < B; ++j) c += (L[j] > tt) ? 1 : 0;
        nAct[tt] = c;
    }
}

// ---------- init h0/c0 (sorted) + bf16 copy into hbR slot 0 ----------
__global__ void k_init_hc(const float* enc_h, const float* enc_c, const int* idx,
                          float* h, float* c, __hip_bfloat16* hbR0){
    int j = blockIdx.x;
    int o = idx[j];
    for (int k = threadIdx.x; k < HID; k += blockDim.x){
        float hv = (k < 512) ? enc_h[o*512 + k] : enc_h[B*512 + o*512 + (k-512)];
        float cv = (k < 512) ? enc_c[o*512 + k] : enc_c[B*512 + o*512 + (k-512)];
        h[j*HID + k] = hv;
        c[j*HID + k] = cv;
        hbR0[j*HID + k] = __float2bfloat16(hv);
    }
}

// ---------- Wcat in per-strip MFMA-fragment order (once) ----------
__global__ void k_cvt_wcat(const float* Wih, const float* Whh, __hip_bfloat16* Wfrag){
    size_t i = (size_t)blockIdx.x*256 + threadIdx.x;
    int e = (int)(i & 7);
    size_t t2 = i >> 3;
    int lane = (int)(t2 & 63);
    size_t t3 = t2 >> 6;
    int kt = (int)(t3 % KT4);
    int strip = (int)(t3 / KT4);
    int n = strip*16 + (lane & 15);
    int r = (n & 3)*HID + (n >> 2);
    int k = kt*32 + (lane >> 4)*8 + e;
    float v = (k < EMB+ENC) ? Wih[(size_t)r*(EMB+ENC) + k]
                            : Whh[(size_t)r*HID + (k - EMB - ENC)];
    Wfrag[i] = __float2bfloat16(v);
}

__global__ void k_bsum(const float* bih, const float* bhh, float* bsum){
    int n = blockIdx.x*256 + threadIdx.x;
    int r = (n & 3)*HID + (n >> 2);
    bsum[n] = bih[r] + bhh[r];
}

__global__ void k_cvt_w2(const float* Wda, const float* bda, const float* Wfb, const float* bfb,
                         __hip_bfloat16* W2, float* bias2){
    int n = blockIdx.x;
    const float* src = (n < ATT) ? (Wda + (size_t)n*HID) : (Wfb + (size_t)(n-ATT)*HID);
    __hip_bfloat16* dst = W2 + (size_t)n*HID;
    for (int k = threadIdx.x; k < HID; k += 256) dst[k] = __float2bfloat16(src[k]);
    if (threadIdx.x == 0) bias2[n] = (n < ATT) ? bda[n] : bfb[n-ATT];
}

__global__ void k_cvt_emb(const float* emb, __hip_bfloat16* emb_bf){
    size_t i = (size_t)blockIdx.x*256 + threadIdx.x;
    emb_bf[i] = __float2bfloat16(emb[i]);
}

__global__ void k_cvt_wea(const float* Wea, __hip_bfloat16* Wea_bf){
    int n = blockIdx.x;
    for (int k = threadIdx.x; k < ENC; k += 256)
        Wea_bf[(size_t)n*ENC + k] = __float2bfloat16(Wea[(size_t)n*ENC + k]);
}

__global__ void k_cvt_img(const float* img, const int* idx, __hip_bfloat16* img_s){
    int j = blockIdx.y;
    int o = idx[j];
    size_t off = (size_t)blockIdx.x*256 + threadIdx.x;
    img_s[(size_t)j*P*ENC + off] = __float2bfloat16(img[(size_t)o*P*ENC + off]);
}

// ---------- att1 (once, MFMA) ----------
__global__ __launch_bounds__(256) void k_att1m(const __hip_bfloat16* img_s, const __hip_bfloat16* Wea_bf,
                                               const float* bea, __hip_bfloat16* att1w){
    int m0 = blockIdx.x * 64, n0 = blockIdx.y * 64;
    int tid = threadIdx.x, w = tid >> 6, l = tid & 63, lm = l & 15, lk = l >> 4;
    const short* ap = (const short*)img_s + (size_t)(m0 + 16*w + lm)*ENC + 8*lk;
    const short* bp = (const short*)Wea_bf + (size_t)(n0 + lm)*ENC + 8*lk;
    f32x4 acc[4];
    #pragma unroll
    for (int nt=0; nt<4; ++nt) acc[nt] = (f32x4){0.f,0.f,0.f,0.f};
    #pragma unroll 4
    for (int kt = 0; kt < ENC/32; ++kt){
        bf16x8 a = *(const bf16x8*)(ap + kt*32);
        #pragma unroll
        for (int nt=0; nt<4; ++nt){
            bf16x8 bb = *(const bf16x8*)(bp + (size_t)nt*16*ENC + kt*32);
            acc[nt] = __builtin_amdgcn_mfma_f32_16x16x32_bf16(a, bb, acc[nt], 0,0,0);
        }
    }
    #pragma unroll
    for (int nt=0; nt<4; ++nt){
        int n = n0 + nt*16 + lm;
        float bv = bea[n];
        #pragma unroll
        for (int r=0; r<4; ++r){
            int m = m0 + 16*w + 4*lk + r;
            att1w[(size_t)m*ATT + n] = __float2bfloat16(acc[nt][r] + bv);
        }
    }
}

// ---------- persistent cooperative scan ----------
struct SP {
    const __hip_bfloat16 *att1w, *img_s, *emb_bf, *Wfrag, *W2;
    const float *bsum, *bias2, *wfa, *bfa;
    const int *sent, *idx, *rank, *lens, *nAct;
    float *D2;
    __hip_bfloat16 *gcR, *hbR;     // rotating: gcR[t], hbR[t] (hbR has T+1 slots)
    float *hF0, *hF1, *cW;
    float *outH, *outA;
    unsigned *barCnt;
};

__global__ __launch_bounds__(1024, 4) void k_scan(SP p){
    __shared__ short WcatL[KT4*64*8];          // 114,688 B, fragment-ordered
    __shared__ union {
        struct { float Dp[4][64][17]; float hS[64][4]; int tokL[64], lensL[64], wLs[64]; } gem;
        struct { float att2L[512]; float wfaL[512]; float red[1024]; float aL[208]; float ctxP[8][512]; } p23;
    } sh;

    int b = blockIdx.x, tid = threadIdx.x;
    int w = tid >> 6, l = tid & 63, lm = l & 15, lk = l >> 4;
    unsigned bk = 0;

    // one-time LDS fill (straight copy, frag order)
    {
        const bf16x8* src = (const bf16x8*)((const short*)p.Wfrag + (size_t)b*KT4*64*8);
        bf16x8* dst = (bf16x8*)WcatL;
        #pragma unroll
        for (int i = 0; i < KT4*64/NTHR; ++i) dst[tid + i*NTHR] = src[tid + i*NTHR];
    }
    __syncthreads();

    float bfa0 = p.bfa[0];

    for (int t = 0; t < T; ++t){
        const __hip_bfloat16* hbIn = p.hbR + (size_t)t*B*HID;          // written at t-1 (volatile) -> fresh L2 fill
        __hip_bfloat16*       hbOut = p.hbR + (size_t)(t+1)*B*HID;
        const __hip_bfloat16* gcT  = p.gcR + (size_t)t*B*ENC;
        const float* hFIn = (t & 1) ? p.hF1 : p.hF0;
        float*       hFOut = (t & 1) ? p.hF0 : p.hF1;
        int nAct = p.nAct[t];

        // ---- P1: D2[64][2560] = h_bf @ W2^T + bias2 ; blocks < 160, 4-way K-split ----
        if (b < N2/16){
            int n0 = b*16;
            int rt = w & 3, kq = w >> 2;
            if (16*rt < nAct){
                const short* ap = (const short*)hbIn + (size_t)(16*rt + lm)*HID + kq*256 + 8*lk;
                const short* bp = (const short*)p.W2 + (size_t)(n0 + lm)*HID + kq*256 + 8*lk;
                f32x4 acc = {0.f,0.f,0.f,0.f};
                #pragma unroll
                for (int kt = 0; kt < 8; ++kt){
                    bf16x8 a = *(const bf16x8*)(ap + kt*32);       // normal cached read
                    bf16x8 bb = *(const bf16x8*)(bp + kt*32);
                    acc = __builtin_amdgcn_mfma_f32_16x16x32_bf16(a, bb, acc, 0,0,0);
                }
                #pragma unroll
                for (int r=0; r<4; ++r) sh.gem.Dp[kq][16*rt + 4*lk + r][lm] = acc[r];
            }
            __syncthreads();
            int m = tid >> 4, nl = tid & 15;
            if (m < nAct){
                stgf(&p.D2[m*N2 + n0 + nl],
                     sh.gem.Dp[0][m][nl] + sh.gem.Dp[1][m][nl]
                   + sh.gem.Dp[2][m][nl] + sh.gem.Dp[3][m][nl] + p.bias2[n0 + nl]);
            }
        }
        gbar(p.barCnt, bk++);

        // ---- P23: e + softmax + context + gc ; block = (j=b&63, q=b>>6) ----
        {
            int j = b & 63, q = b >> 6;
            int o = p.idx[j], wj = p.rank[j], lj = p.lens[o];
            if (t < lj){
                if (tid < 512){
                    sh.p23.att2L[tid] = ldgf(&p.D2[j*N2 + tid]);
                    sh.p23.wfaL[tid]  = p.wfa[tid];
                }
                __syncthreads();

                int pp = tid & 255, ah = tid >> 8;
                float acc = 0.f;
                if (pp < P){
                    const short* ar = (const short*)p.att1w + (size_t)(j*P + pp)*ATT + ah*128;
                    #pragma unroll 8
                    for (int k8 = 0; k8 < 16; ++k8){
                        bf16x8 v = *(const bf16x8*)(ar + k8*8);
                        #pragma unroll
                        for (int z=0; z<8; ++z){
                            int a = ah*128 + k8*8 + z;
                            acc += fmaxf(bfu(v[z]) + sh.p23.att2L[a], 0.f) * sh.p23.wfaL[a];
                        }
                    }
                }
                sh.p23.red[tid] = acc;
                __syncthreads();
                float e = -1e30f;
                if (tid < P) e = sh.p23.red[tid] + sh.p23.red[tid+256] + sh.p23.red[tid+512] + sh.p23.red[tid+768] + bfa0;
                __syncthreads();
                sh.p23.red[tid] = (tid < P) ? e : -1e30f;
                __syncthreads();
                for (int s = 512; s > 0; s >>= 1){
                    if (tid < s) sh.p23.red[tid] = fmaxf(sh.p23.red[tid], sh.p23.red[tid+s]);
                    __syncthreads();
                }
                float m = sh.p23.red[0];
                __syncthreads();
                float ex = (tid < P) ? __expf(e - m) : 0.f;
                sh.p23.red[tid] = ex;
                __syncthreads();
                for (int s = 512; s > 0; s >>= 1){
                    if (tid < s) sh.p23.red[tid] += sh.p23.red[tid+s];
                    __syncthreads();
                }
                float ssum = sh.p23.red[0];
                if (tid < P){
                    float alpha = ex / ssum;
                    sh.p23.aL[tid] = alpha;
                    if (q == 0) p.outA[((size_t)(wj*T + t))*P + tid] = alpha;
                }
                if (tid >= P && tid < 208) sh.p23.aL[tid] = 0.f;
                __syncthreads();

                const short* ib = (const short*)p.img_s + (size_t)j*P*ENC + q*512 + l*8;
                float a8[8];
                #pragma unroll
                for (int z=0; z<8; ++z) a8[z] = 0.f;
                #pragma unroll 4
                for (int i = 0; i < 13; ++i){
                    int pp2 = w + 16*i;
                    int pr = (pp2 < P) ? pp2 : 0;
                    bf16x8 v = *(const bf16x8*)(ib + (size_t)pr*ENC);
                    float al = sh.p23.aL[pp2];
                    #pragma unroll
                    for (int z=0; z<8; ++z) a8[z] += al * bfu(v[z]);
                }
                if (w < 8){
                    #pragma unroll
                    for (int z=0; z<8; ++z) sh.p23.ctxP[w][l*8+z] = a8[z];
                }
                __syncthreads();
                if (w >= 8){
                    #pragma unroll
                    for (int z=0; z<8; ++z) sh.p23.ctxP[w-8][l*8+z] += a8[z];
                }
                __syncthreads();
                if (tid < 256){
                    int d0 = 2*tid;
                    float c0 = 0.f, c1 = 0.f;
                    #pragma unroll
                    for (int r=0; r<8; ++r){ c0 += sh.p23.ctxP[r][d0]; c1 += sh.p23.ctxP[r][d0+1]; }
                    int eg0 = q*512 + d0;
                    float g0 = sigm(ldgf(&p.D2[j*N2 + ATT + eg0]));
                    float g1 = sigm(ldgf(&p.D2[j*N2 + ATT + eg0 + 1]));
                    stgu((unsigned*)((short*)gcT + j*ENC + eg0), pkbf(g0*c0, g1*c1));
                }
            } else {
                if (q == 0 && tid < P) p.outA[((size_t)(wj*T + t))*P + tid] = 0.f;
            }
        }
        gbar(p.barCnt, bk++);

        // ---- P4: gates GEMM (4-way K-split, B from LDS, A normal-cached) + LSTM ----
        {
            if (tid < 64){
                int o = p.idx[tid];
                sh.gem.tokL[tid] = p.sent[o*T + t];
                sh.gem.lensL[tid] = p.lens[o];
                sh.gem.wLs[tid] = p.rank[tid];
            }
            __syncthreads();
            int rt = w & 3, kq = w >> 2;
            if (16*rt < nAct){
                int mrow = 16*rt + lm;
                int tok = sh.gem.tokL[mrow];
                const short* aEmb = (const short*)p.emb_bf + (size_t)tok*EMB + 8*lk;
                const short* aGc  = (const short*)gcT + (size_t)mrow*ENC + 8*lk;
                const short* aH   = (const short*)hbIn + (size_t)mrow*HID + 8*lk;
                const bf16x8* BL = (const bf16x8*)WcatL;
                f32x4 acc = {0.f,0.f,0.f,0.f};
                if (kq == 0){
                    #pragma unroll 8
                    for (int kt = 0; kt < 16; ++kt){
                        bf16x8 a = *(const bf16x8*)(aEmb + kt*32);
                        acc = __builtin_amdgcn_mfma_f32_16x16x32_bf16(a, BL[kt*64 + l], acc, 0,0,0);
                    }
                    #pragma unroll 6
                    for (int kt = 16; kt < 28; ++kt){
                        bf16x8 a = *(const bf16x8*)(aGc + (kt-16)*32);
                        acc = __builtin_amdgcn_mfma_f32_16x16x32_bf16(a, BL[kt*64 + l], acc, 0,0,0);
                    }
                } else if (kq == 1){
                    #pragma unroll 7
                    for (int kt = 28; kt < 56; ++kt){
                        bf16x8 a = *(const bf16x8*)(aGc + (kt-16)*32);
                        acc = __builtin_amdgcn_mfma_f32_16x16x32_bf16(a, BL[kt*64 + l], acc, 0,0,0);
                    }
                } else if (kq == 2){
                    #pragma unroll 6
                    for (int kt = 56; kt < 80; ++kt){
                        bf16x8 a = *(const bf16x8*)(aGc + (kt-16)*32);
                        acc = __builtin_amdgcn_mfma_f32_16x16x32_bf16(a, BL[kt*64 + l], acc, 0,0,0);
                    }
                    #pragma unroll
                    for (int kt = 80; kt < 84; ++kt){
                        bf16x8 a = *(const bf16x8*)(aH + (kt-80)*32);
                        acc = __builtin_amdgcn_mfma_f32_16x16x32_bf16(a, BL[kt*64 + l], acc, 0,0,0);
                    }
                } else {
                    #pragma unroll 7
                    for (int kt = 84; kt < 112; ++kt){
                        bf16x8 a = *(const bf16x8*)(aH + (kt-80)*32);
                        acc = __builtin_amdgcn_mfma_f32_16x16x32_bf16(a, BL[kt*64 + l], acc, 0,0,0);
                    }
                }
                #pragma unroll
                for (int r=0; r<4; ++r) sh.gem.Dp[kq][16*rt + 4*lk + r][lm] = acc[r];
            }
            __syncthreads();
            if (tid < 256){
                int j2 = tid & 63, du = tid >> 6;
                int u = 4*b + du;
                float g4[4];
                #pragma unroll
                for (int g=0; g<4; ++g){
                    int nl = 4*du + g;
                    g4[g] = sh.gem.Dp[0][j2][nl] + sh.gem.Dp[1][j2][nl]
                          + sh.gem.Dp[2][j2][nl] + sh.gem.Dp[3][j2][nl] + p.bsum[16*b + nl];
                }
                float ig = sigm(g4[0]), fg = sigm(g4[1]), gg = tanhf(g4[2]), og = sigm(g4[3]);
                float cOld = p.cW[j2*HID + u];
                float cNew = fg*cOld + ig*gg;
                float hNew = og*tanhf(cNew);
                bool active = (t < sh.gem.lensL[j2]);
                float hOld = hFIn[j2*HID + u];
                float hKeep = active ? hNew : hOld;
                hFOut[j2*HID + u] = hKeep;
                sh.gem.hS[j2][du] = hKeep;
                p.cW[j2*HID + u] = active ? cNew : cOld;
                p.outH[((size_t)sh.gem.wLs[j2]*T + t)*HID + u] = active ? hNew : 0.f;
            }
            __syncthreads();
            if (tid < 128){
                int j2 = tid & 63, dp = tid >> 6;
                int u0 = 4*b + 2*dp;
                stgu((unsigned*)((short*)hbOut + j2*HID + u0),
                     pkbf(sh.gem.hS[j2][2*dp], sh.gem.hS[j2][2*dp+1]));
            }
        }
        gbar(p.barCnt, bk++);
    }
}

extern "C" void kernel_launch(void* const* d_in, const int* in_sizes, int n_in,
                              void* d_out, int out_size, void* d_ws, size_t ws_size,
                              hipStream_t stream) {
    const float* img   = (const float*)d_in[0];
    const int*   sent  = (const int*)  d_in[1];
    const float* enc_h = (const float*)d_in[2];
    const float* enc_c = (const float*)d_in[3];
    const int*   lens  = (const int*)  d_in[4];
    const float* emb   = (const float*)d_in[5];
    const float* Wea   = (const float*)d_in[6];
    const float* bea   = (const float*)d_in[7];
    const float* Wda   = (const float*)d_in[8];
    const float* bda   = (const float*)d_in[9];
    const float* wfa   = (const float*)d_in[10];
    const float* bfa   = (const float*)d_in[11];
    const float* Wfb   = (const float*)d_in[12];
    const float* bfb   = (const float*)d_in[13];
    const float* Wih   = (const float*)d_in[14];
    const float* bih   = (const float*)d_in[15];
    const float* Whh   = (const float*)d_in[16];
    const float* bhh   = (const float*)d_in[17];

    float* outH = (float*)d_out;                       // [B,T,HID] f32
    float* outA = outH + (size_t)B*T*HID;              // [B,T,P]  f32

    char* wsb = (char*)d_ws;
    size_t off = 0;
    int* idxW  = (int*)(wsb + off); off += 256;
    int* rankW = (int*)(wsb + off); off += 256;
    int* nActW = (int*)(wsb + off); off += 1024;
    unsigned* barCnt = (unsigned*)(wsb + off); off += 32768;
    __hip_bfloat16* att1w = (__hip_bfloat16*)(wsb + off); off += (size_t)B*P*ATT*2;       // 12.85MB
    __hip_bfloat16* img_s = (__hip_bfloat16*)(wsb + off); off += (size_t)B*P*ENC*2;       // 51.38MB
    __hip_bfloat16* emb_bf= (__hip_bfloat16*)(wsb + off); off += (size_t)10000*EMB*2;     // 10.24MB
    __hip_bfloat16* Wfrag = (__hip_bfloat16*)(wsb + off); off += (size_t)4*HID*KTOT*2;    // 29.36MB
    __hip_bfloat16* W2    = (__hip_bfloat16*)(wsb + off); off += (size_t)N2*HID*2;        // 5.24MB
    __hip_bfloat16* Wea_bf= (__hip_bfloat16*)(wsb + off); off += (size_t)ATT*ENC*2;       // 2.10MB (prologue-only)
    float* bsum  = (float*)(wsb + off); off += 4*HID*4;
    float* bias2 = (float*)(wsb + off); off += N2*4;
    float* hA    = (float*)(wsb + off); off += B*HID*4;
    float* hB    = (float*)(wsb + off); off += B*HID*4;
    float* cWs   = (float*)(wsb + off); off += B*HID*4;
    float* D2    = (float*)(wsb + off); off += (size_t)B*N2*4;
    __hip_bfloat16* gcR = (__hip_bfloat16*)(wsb + off); off += (size_t)T*B*ENC*2;         // 41.9MB rotating
    __hip_bfloat16* hbR = (__hip_bfloat16*)(wsb + off); off += (size_t)(T+1)*B*HID*2;     // 21.1MB rotating

    k_sort<<<1, 64, 0, stream>>>(lens, idxW, rankW, barCnt, nActW);
    k_init_hc<<<B, 256, 0, stream>>>(enc_h, enc_c, idxW, hA, cWs, hbR);
    k_cvt_wcat<<<57344, 256, 0, stream>>>(Wih, Whh, Wfrag);
    k_bsum<<<16, 256, 0, stream>>>(bih, bhh, bsum);
    k_cvt_w2<<<N2, 256, 0, stream>>>(Wda, bda, Wfb, bfb, W2, bias2);
    k_cvt_emb<<<20000, 256, 0, stream>>>(emb, emb_bf);
    k_cvt_wea<<<ATT, 256, 0, stream>>>(Wea, Wea_bf);
    k_cvt_img<<<dim3(P*ENC/256, B), 256, 0, stream>>>(img, idxW, img_s);
    k_att1m<<<dim3((B*P)/64, ATT/64), 256, 0, stream>>>(img_s, Wea_bf, bea, att1w);

    SP sp;
    sp.att1w = att1w; sp.img_s = img_s; sp.emb_bf = emb_bf; sp.Wfrag = Wfrag; sp.W2 = W2;
    sp.bsum = bsum; sp.bias2 = bias2; sp.wfa = wfa; sp.bfa = bfa;
    sp.sent = sent; sp.idx = idxW; sp.rank = rankW; sp.lens = lens; sp.nAct = nActW;
    sp.D2 = D2; sp.gcR = gcR; sp.hbR = hbR;
    sp.hF0 = hA; sp.hF1 = hB; sp.cW = cWs;
    sp.outH = outH; sp.outA = outA;
    sp.barCnt = barCnt;

    void* args[] = { &sp };
    hipLaunchCooperativeKernel(reinterpret_cast<void*>(k_scan), dim3(NBLK), dim3(NTHR),
                               args, 0, stream);
}

// Round 14
// 7031.487 us; speedup vs baseline: 2.0709x; 1.0598x over previous
//
#include <hip/hip_runtime.h>
#include <hip/hip_bf16.h>
#include <math.h>

#define B 64
#define T 160
#define P 196
#define ENC 2048
#define ATT 512
#define EMB 512
#define HID 1024
#define KTOT 3584   // EMB + ENC + HID
#define N2 2560     // ATT + ENC
#define KT4 112     // KTOT/32
#define NTHR 1024
#define NBLK 256
#define NGRP 16
#define GRPSZ (NBLK/NGRP)

typedef __attribute__((ext_vector_type(8))) short bf16x8;
typedef __attribute__((ext_vector_type(4))) float f32x4;
typedef float __attribute__((ext_vector_type(4))) vf4;

__device__ __forceinline__ float sigm(float x){ return 1.0f/(1.0f+__expf(-x)); }
__device__ __forceinline__ float bfu(short s){ return __uint_as_float(((unsigned)(unsigned short)s) << 16); }

// ---- MALL-coherent movement for cross-block data (volatile => sc0 sc1) ----
__device__ __forceinline__ float ldgf(const float* p){ return *(const volatile float*)p; }
__device__ __forceinline__ void stgf(float* p, float v){ *(volatile float*)p = v; }
__device__ __forceinline__ void stgu(unsigned* p, unsigned v){ *(volatile unsigned*)p = v; }
__device__ __forceinline__ unsigned pkbf(float a, float b){
    unsigned ua = (unsigned)__bfloat16_as_ushort(__float2bfloat16(a));
    unsigned ub = (unsigned)__bfloat16_as_ushort(__float2bfloat16(b));
    return ua | (ub << 16);
}

// ---- split grid barrier with 16-way release fan-out ----
// barCnt slots (u32, stride 256 words = 1KB): [0..15] group counters,
// [16] top counter, [17..32] release lines. Monotone, round k.
__device__ __forceinline__ void gbar_arrive(unsigned* bar, unsigned k){
    asm volatile("s_waitcnt vmcnt(0)" ::: "memory");   // our stores visible before arrival
    __syncthreads();
    if (threadIdx.x == 0){
        unsigned g = blockIdx.x & (NGRP-1);
        unsigned old = __hip_atomic_fetch_add(bar + g*256, 1u, __ATOMIC_RELAXED, __HIP_MEMORY_SCOPE_AGENT);
        if (old == (k + 1u)*GRPSZ - 1u){
            __hip_atomic_fetch_add(bar + NGRP*256, 1u, __ATOMIC_RELAXED, __HIP_MEMORY_SCOPE_AGENT);
        }
    }
}
__device__ __forceinline__ void gbar_wait(unsigned* bar, unsigned k){
    if (threadIdx.x == 0){
        unsigned b = blockIdx.x;
        if (b < NGRP){
            // relayer for group b: poll top (only 16 pollers), then fan out
            volatile unsigned* top = bar + NGRP*256;
            while (*top < (k + 1u)*NGRP) __builtin_amdgcn_s_sleep(2);
            *(volatile unsigned*)(bar + (NGRP + 1 + b)*256) = k + 1u;
        } else {
            volatile unsigned* rel = bar + (NGRP + 1 + (b & (NGRP-1)))*256;
            while (*rel < k + 1u) __builtin_amdgcn_s_sleep(2);
        }
    }
    __syncthreads();
    asm volatile("" ::: "memory");
}
__device__ __forceinline__ void gbar(unsigned* bar, unsigned k){
    gbar_arrive(bar, k);
    gbar_wait(bar, k);
}

// ---------- sort + nAct table ----------
__global__ void k_sort(const int* lens, int* idx, int* rank, unsigned* barCnt, int* nAct){
    __shared__ int L[B];
    int i = threadIdx.x;
    L[i] = lens[i];
    if (i < 33) barCnt[i*256] = 0u;     // 16 group + top + 16 release
    __syncthreads();
    int li = L[i];
    int r = 0;
    for (int j = 0; j < B; ++j){
        int lj = L[j];
        if (lj > li || (lj == li && j < i)) r++;
    }
    rank[i] = r;
    idx[r] = i;
    for (int tt = i; tt < T; tt += B){
        int c = 0;
        for (int j = 0; j < B; ++j) c += (L[j] > tt) ? 1 : 0;
        nAct[tt] = c;
    }
}

// ---------- init h0/c0 (sorted) + bf16 copy into hbR slot 0 ----------
__global__ void k_init_hc(const float* enc_h, const float* enc_c, const int* idx,
                          float* h, float* c, __hip_bfloat16* hbR0){
    int j = blockIdx.x;
    int o = idx[j];
    for (int k = threadIdx.x; k < HID; k += blockDim.x){
        float hv = (k < 512) ? enc_h[o*512 + k] : enc_h[B*512 + o*512 + (k-512)];
        float cv = (k < 512) ? enc_c[o*512 + k] : enc_c[B*512 + o*512 + (k-512)];
        h[j*HID + k] = hv;
        c[j*HID + k] = cv;
        hbR0[j*HID + k] = __float2bfloat16(hv);
    }
}

// ---------- Wcat in per-strip MFMA-fragment order (once) ----------
__global__ void k_cvt_wcat(const float* Wih, const float* Whh, __hip_bfloat16* Wfrag){
    size_t i = (size_t)blockIdx.x*256 + threadIdx.x;
    int e = (int)(i & 7);
    size_t t2 = i >> 3;
    int lane = (int)(t2 & 63);
    size_t t3 = t2 >> 6;
    int kt = (int)(t3 % KT4);
    int strip = (int)(t3 / KT4);
    int n = strip*16 + (lane & 15);
    int r = (n & 3)*HID + (n >> 2);
    int k = kt*32 + (lane >> 4)*8 + e;
    float v = (k < EMB+ENC) ? Wih[(size_t)r*(EMB+ENC) + k]
                            : Whh[(size_t)r*HID + (k - EMB - ENC)];
    Wfrag[i] = __float2bfloat16(v);
}

__global__ void k_bsum(const float* bih, const float* bhh, float* bsum){
    int n = blockIdx.x*256 + threadIdx.x;
    int r = (n & 3)*HID + (n >> 2);
    bsum[n] = bih[r] + bhh[r];
}

__global__ void k_cvt_w2(const float* Wda, const float* bda, const float* Wfb, const float* bfb,
                         __hip_bfloat16* W2, float* bias2){
    int n = blockIdx.x;
    const float* src = (n < ATT) ? (Wda + (size_t)n*HID) : (Wfb + (size_t)(n-ATT)*HID);
    __hip_bfloat16* dst = W2 + (size_t)n*HID;
    for (int k = threadIdx.x; k < HID; k += 256) dst[k] = __float2bfloat16(src[k]);
    if (threadIdx.x == 0) bias2[n] = (n < ATT) ? bda[n] : bfb[n-ATT];
}

__global__ void k_cvt_emb(const float* emb, __hip_bfloat16* emb_bf){
    size_t i = (size_t)blockIdx.x*256 + threadIdx.x;
    emb_bf[i] = __float2bfloat16(emb[i]);
}

__global__ void k_cvt_wea(const float* Wea, __hip_bfloat16* Wea_bf){
    int n = blockIdx.x;
    for (int k = threadIdx.x; k < ENC; k += 256)
        Wea_bf[(size_t)n*ENC + k] = __float2bfloat16(Wea[(size_t)n*ENC + k]);
}

__global__ void k_cvt_img(const float* img, const int* idx, __hip_bfloat16* img_s){
    int j = blockIdx.y;
    int o = idx[j];
    size_t off = (size_t)blockIdx.x*256 + threadIdx.x;
    img_s[(size_t)j*P*ENC + off] = __float2bfloat16(img[(size_t)o*P*ENC + off]);
}

// ---------- att1 (once, MFMA) ----------
__global__ __launch_bounds__(256) void k_att1m(const __hip_bfloat16* img_s, const __hip_bfloat16* Wea_bf,
                                               const float* bea, __hip_bfloat16* att1w){
    int m0 = blockIdx.x * 64, n0 = blockIdx.y * 64;
    int tid = threadIdx.x, w = tid >> 6, l = tid & 63, lm = l & 15, lk = l >> 4;
    const short* ap = (const short*)img_s + (size_t)(m0 + 16*w + lm)*ENC + 8*lk;
    const short* bp = (const short*)Wea_bf + (size_t)(n0 + lm)*ENC + 8*lk;
    f32x4 acc[4];
    #pragma unroll
    for (int nt=0; nt<4; ++nt) acc[nt] = (f32x4){0.f,0.f,0.f,0.f};
    #pragma unroll 4
    for (int kt = 0; kt < ENC/32; ++kt){
        bf16x8 a = *(const bf16x8*)(ap + kt*32);
        #pragma unroll
        for (int nt=0; nt<4; ++nt){
            bf16x8 bb = *(const bf16x8*)(bp + (size_t)nt*16*ENC + kt*32);
            acc[nt] = __builtin_amdgcn_mfma_f32_16x16x32_bf16(a, bb, acc[nt], 0,0,0);
        }
    }
    #pragma unroll
    for (int nt=0; nt<4; ++nt){
        int n = n0 + nt*16 + lm;
        float bv = bea[n];
        #pragma unroll
        for (int r=0; r<4; ++r){
            int m = m0 + 16*w + 4*lk + r;
            att1w[(size_t)m*ATT + n] = __float2bfloat16(acc[nt][r] + bv);
        }
    }
}

// ---------- persistent cooperative scan ----------
struct SP {
    const __hip_bfloat16 *att1w, *img_s, *emb_bf, *Wfrag, *W2;
    const float *bsum, *bias2, *wfa, *bfa;
    const int *sent, *idx, *rank, *lens, *nAct;
    float *D2;
    __hip_bfloat16 *gcR, *hbR;     // rotating: gcR[t], hbR[t] (hbR has T+1 slots)
    float *hF0, *hF1, *cW;
    float *outH, *outA;
    unsigned *barCnt;
};

__global__ __launch_bounds__(1024, 4) void k_scan(SP p){
    __shared__ short WcatL[KT4*64*8];          // 114,688 B, fragment-ordered
    __shared__ union {
        struct { float Dp[4][64][17]; float hS[64][4]; int tokL[64], lensL[64], wLs[64]; } gem;
        struct { float att2L[512]; float wfaL[512]; float red[1024]; float aL[208]; float ctxP[8][512]; } p23;
    } sh;

    int b = blockIdx.x, tid = threadIdx.x;
    int w = tid >> 6, l = tid & 63, lm = l & 15, lk = l >> 4;
    unsigned bk = 0;

    // one-time LDS fill (straight copy, frag order)
    {
        const bf16x8* src = (const bf16x8*)((const short*)p.Wfrag + (size_t)b*KT4*64*8);
        bf16x8* dst = (bf16x8*)WcatL;
        #pragma unroll
        for (int i = 0; i < KT4*64/NTHR; ++i) dst[tid + i*NTHR] = src[tid + i*NTHR];
    }
    __syncthreads();

    float bfa0 = p.bfa[0];

    for (int t = 0; t < T; ++t){
        const __hip_bfloat16* hbIn = p.hbR + (size_t)t*B*HID;
        __hip_bfloat16*       hbOut = p.hbR + (size_t)(t+1)*B*HID;
        const __hip_bfloat16* gcT  = p.gcR + (size_t)t*B*ENC;
        const float* hFIn = (t & 1) ? p.hF1 : p.hF0;
        float*       hFOut = (t & 1) ? p.hF0 : p.hF1;
        int nAct = p.nAct[t];

        // ---- P1: D2[64][2560] = h_bf @ W2^T + bias2 ; blocks < 160, 4-way K-split ----
        if (b < N2/16){
            int n0 = b*16;
            int rt = w & 3, kq = w >> 2;
            if (16*rt < nAct){
                const short* ap = (const short*)hbIn + (size_t)(16*rt + lm)*HID + kq*256 + 8*lk;
                const short* bp = (const short*)p.W2 + (size_t)(n0 + lm)*HID + kq*256 + 8*lk;
                f32x4 acc = {0.f,0.f,0.f,0.f};
                #pragma unroll
                for (int kt = 0; kt < 8; ++kt){
                    bf16x8 a = *(const bf16x8*)(ap + kt*32);
                    bf16x8 bb = *(const bf16x8*)(bp + kt*32);
                    acc = __builtin_amdgcn_mfma_f32_16x16x32_bf16(a, bb, acc, 0,0,0);
                }
                #pragma unroll
                for (int r=0; r<4; ++r) sh.gem.Dp[kq][16*rt + 4*lk + r][lm] = acc[r];
            }
            __syncthreads();
            int m = tid >> 4, nl = tid & 15;
            if (m < nAct){
                stgf(&p.D2[m*N2 + n0 + nl],
                     sh.gem.Dp[0][m][nl] + sh.gem.Dp[1][m][nl]
                   + sh.gem.Dp[2][m][nl] + sh.gem.Dp[3][m][nl] + p.bias2[n0 + nl]);
            }
        }
        gbar(p.barCnt, bk); bk++;

        // ---- P23: e + softmax + context + gc ; block = (j=b&63, q=b>>6) ----
        int jj = b & 63, qq = b >> 6;
        int oo = p.idx[jj], wjj = p.rank[jj], ljj = p.lens[oo];
        {
            if (t < ljj){
                if (tid < 512){
                    sh.p23.att2L[tid] = ldgf(&p.D2[jj*N2 + tid]);
                    sh.p23.wfaL[tid]  = p.wfa[tid];
                }
                __syncthreads();

                int pp = tid & 255, ah = tid >> 8;
                float acc = 0.f;
                if (pp < P){
                    const short* ar = (const short*)p.att1w + (size_t)(jj*P + pp)*ATT + ah*128;
                    #pragma unroll 8
                    for (int k8 = 0; k8 < 16; ++k8){
                        bf16x8 v = *(const bf16x8*)(ar + k8*8);
                        #pragma unroll
                        for (int z=0; z<8; ++z){
                            int a = ah*128 + k8*8 + z;
                            acc += fmaxf(bfu(v[z]) + sh.p23.att2L[a], 0.f) * sh.p23.wfaL[a];
                        }
                    }
                }
                sh.p23.red[tid] = acc;
                __syncthreads();
                float e = -1e30f;
                if (tid < P) e = sh.p23.red[tid] + sh.p23.red[tid+256] + sh.p23.red[tid+512] + sh.p23.red[tid+768] + bfa0;
                __syncthreads();
                sh.p23.red[tid] = (tid < P) ? e : -1e30f;
                __syncthreads();
                for (int s = 512; s > 0; s >>= 1){
                    if (tid < s) sh.p23.red[tid] = fmaxf(sh.p23.red[tid], sh.p23.red[tid+s]);
                    __syncthreads();
                }
                float m = sh.p23.red[0];
                __syncthreads();
                float ex = (tid < P) ? __expf(e - m) : 0.f;
                sh.p23.red[tid] = ex;
                __syncthreads();
                for (int s = 512; s > 0; s >>= 1){
                    if (tid < s) sh.p23.red[tid] += sh.p23.red[tid+s];
                    __syncthreads();
                }
                float ssum = sh.p23.red[0];
                if (tid < P) sh.p23.aL[tid] = ex / ssum;
                if (tid >= P && tid < 208) sh.p23.aL[tid] = 0.f;
                __syncthreads();

                const short* ib = (const short*)p.img_s + (size_t)jj*P*ENC + qq*512 + l*8;
                float a8[8];
                #pragma unroll
                for (int z=0; z<8; ++z) a8[z] = 0.f;
                #pragma unroll 4
                for (int i = 0; i < 13; ++i){
                    int pp2 = w + 16*i;
                    int pr = (pp2 < P) ? pp2 : 0;
                    bf16x8 v = *(const bf16x8*)(ib + (size_t)pr*ENC);
                    float al = sh.p23.aL[pp2];
                    #pragma unroll
                    for (int z=0; z<8; ++z) a8[z] += al * bfu(v[z]);
                }
                if (w < 8){
                    #pragma unroll
                    for (int z=0; z<8; ++z) sh.p23.ctxP[w][l*8+z] = a8[z];
                }
                __syncthreads();
                if (w >= 8){
                    #pragma unroll
                    for (int z=0; z<8; ++z) sh.p23.ctxP[w-8][l*8+z] += a8[z];
                }
                __syncthreads();
                if (tid < 256){
                    int d0 = 2*tid;
                    float c0 = 0.f, c1 = 0.f;
                    #pragma unroll
                    for (int r=0; r<8; ++r){ c0 += sh.p23.ctxP[r][d0]; c1 += sh.p23.ctxP[r][d0+1]; }
                    int eg0 = qq*512 + d0;
                    float g0 = sigm(ldgf(&p.D2[jj*N2 + ATT + eg0]));
                    float g1 = sigm(ldgf(&p.D2[jj*N2 + ATT + eg0 + 1]));
                    stgu((unsigned*)((short*)gcT + jj*ENC + eg0), pkbf(g0*c0, g1*c1));
                }
            }
        }
        gbar_arrive(p.barCnt, bk);     // gc visible; do independent work in the wait shadow

        // outA write (external-only) in barrier shadow
        if (qq == 0 && tid < P){
            float av = (t < ljj) ? sh.p23.aL[tid] : 0.f;
            p.outA[((size_t)(wjj*T + t))*P + tid] = av;
        }
        __syncthreads();               // close p23 LDS usage before gem reuse

        // ---- P4 prelude + non-gc MFMA (emb + h segments) in barrier shadow ----
        if (tid < 64){
            int o = p.idx[tid];
            sh.gem.tokL[tid] = p.sent[o*T + t];
            sh.gem.lensL[tid] = p.lens[o];
            sh.gem.wLs[tid] = p.rank[tid];
        }
        __syncthreads();
        {
            int rt = w & 3, kq = w >> 2;
            bool act = (16*rt < nAct);
            int mrow = 16*rt + lm;
            f32x4 acc = {0.f,0.f,0.f,0.f};
            const short* aEmb = 0; const short* aGc = 0; const short* aH = 0;
            const bf16x8* BL = (const bf16x8*)WcatL;
            if (act){
                int tok = sh.gem.tokL[mrow];
                aEmb = (const short*)p.emb_bf + (size_t)tok*EMB + 8*lk;
                aGc  = (const short*)gcT + (size_t)mrow*ENC + 8*lk;
                aH   = (const short*)hbIn + (size_t)mrow*HID + 8*lk;
                if (kq == 0){
                    #pragma unroll 8
                    for (int kt = 0; kt < 16; ++kt){
                        bf16x8 a = *(const bf16x8*)(aEmb + kt*32);
                        acc = __builtin_amdgcn_mfma_f32_16x16x32_bf16(a, BL[kt*64 + l], acc, 0,0,0);
                    }
                } else if (kq == 2){
                    #pragma unroll
                    for (int kt = 80; kt < 84; ++kt){
                        bf16x8 a = *(const bf16x8*)(aH + (kt-80)*32);
                        acc = __builtin_amdgcn_mfma_f32_16x16x32_bf16(a, BL[kt*64 + l], acc, 0,0,0);
                    }
                } else if (kq == 3){
                    #pragma unroll 7
                    for (int kt = 84; kt < 112; ++kt){
                        bf16x8 a = *(const bf16x8*)(aH + (kt-80)*32);
                        acc = __builtin_amdgcn_mfma_f32_16x16x32_bf16(a, BL[kt*64 + l], acc, 0,0,0);
                    }
                }
            }
            gbar_wait(p.barCnt, bk); bk++;    // gc now ready

            if (act){
                if (kq == 0){
                    #pragma unroll 6
                    for (int kt = 16; kt < 28; ++kt){
                        bf16x8 a = *(const bf16x8*)(aGc + (kt-16)*32);
                        acc = __builtin_amdgcn_mfma_f32_16x16x32_bf16(a, BL[kt*64 + l], acc, 0,0,0);
                    }
                } else if (kq == 1){
                    #pragma unroll 7
                    for (int kt = 28; kt < 56; ++kt){
                        bf16x8 a = *(const bf16x8*)(aGc + (kt-16)*32);
                        acc = __builtin_amdgcn_mfma_f32_16x16x32_bf16(a, BL[kt*64 + l], acc, 0,0,0);
                    }
                } else if (kq == 2){
                    #pragma unroll 6
                    for (int kt = 56; kt < 80; ++kt){
                        bf16x8 a = *(const bf16x8*)(aGc + (kt-16)*32);
                        acc = __builtin_amdgcn_mfma_f32_16x16x32_bf16(a, BL[kt*64 + l], acc, 0,0,0);
                    }
                }
                #pragma unroll
                for (int r=0; r<4; ++r) sh.gem.Dp[kq][16*rt + 4*lk + r][lm] = acc[r];
            }
        }
        __syncthreads();

        // ---- LSTM pointwise ----
        int j2 = tid & 63, du = tid >> 6;
        int u = 4*b + du;
        float cNew = 0.f, hNew = 0.f, hKeep = 0.f, cOld = 0.f;
        bool active = false;
        if (tid < 256){
            float g4[4];
            #pragma unroll
            for (int g=0; g<4; ++g){
                int nl = 4*du + g;
                g4[g] = sh.gem.Dp[0][j2][nl] + sh.gem.Dp[1][j2][nl]
                      + sh.gem.Dp[2][j2][nl] + sh.gem.Dp[3][j2][nl] + p.bsum[16*b + nl];
            }
            float ig = sigm(g4[0]), fg = sigm(g4[1]), gg = tanhf(g4[2]), og = sigm(g4[3]);
            cOld = p.cW[j2*HID + u];
            cNew = fg*cOld + ig*gg;
            hNew = og*tanhf(cNew);
            active = (t < sh.gem.lensL[j2]);
            float hOld = hFIn[j2*HID + u];
            hKeep = active ? hNew : hOld;
            sh.gem.hS[j2][du] = hKeep;
        }
        __syncthreads();
        if (tid < 128){
            int jb = tid & 63, dp = tid >> 6;
            int u0 = 4*b + 2*dp;
            stgu((unsigned*)((short*)hbOut + jb*HID + u0),
                 pkbf(sh.gem.hS[jb][2*dp], sh.gem.hS[jb][2*dp+1]));
        }
        gbar_arrive(p.barCnt, bk);     // h(t+1) visible; private/external stores in shadow
        if (tid < 256){
            p.cW[j2*HID + u] = active ? cNew : cOld;
            hFOut[j2*HID + u] = hKeep;
            p.outH[((size_t)sh.gem.wLs[j2]*T + t)*HID + u] = active ? hNew : 0.f;
        }
        gbar_wait(p.barCnt, bk); bk++;
    }
}

extern "C" void kernel_launch(void* const* d_in, const int* in_sizes, int n_in,
                              void* d_out, int out_size, void* d_ws, size_t ws_size,
                              hipStream_t stream) {
    const float* img   = (const float*)d_in[0];
    const int*   sent  = (const int*)  d_in[1];
    const float* enc_h = (const float*)d_in[2];
    const float* enc_c = (const float*)d_in[3];
    const int*   lens  = (const int*)  d_in[4];
    const float* emb   = (const float*)d_in[5];
    const float* Wea   = (const float*)d_in[6];
    const float* bea   = (const float*)d_in[7];
    const float* Wda   = (const float*)d_in[8];
    const float* bda   = (const float*)d_in[9];
    const float* wfa   = (const float*)d_in[10];
    const float* bfa   = (const float*)d_in[11];
    const float* Wfb   = (const float*)d_in[12];
    const float* bfb   = (const float*)d_in[13];
    const float* Wih   = (const float*)d_in[14];
    const float* bih   = (const float*)d_in[15];
    const float* Whh   = (const float*)d_in[16];
    const float* bhh   = (const float*)d_in[17];

    float* outH = (float*)d_out;                       // [B,T,HID] f32
    float* outA = outH + (size_t)B*T*HID;              // [B,T,P]  f32

    char* wsb = (char*)d_ws;
    size_t off = 0;
    int* idxW  = (int*)(wsb + off); off += 256;
    int* rankW = (int*)(wsb + off); off += 256;
    int* nActW = (int*)(wsb + off); off += 1024;
    unsigned* barCnt = (unsigned*)(wsb + off); off += 36864;   // 33 slots x 1KB
    __hip_bfloat16* att1w = (__hip_bfloat16*)(wsb + off); off += (size_t)B*P*ATT*2;       // 12.85MB
    __hip_bfloat16* img_s = (__hip_bfloat16*)(wsb + off); off += (size_t)B*P*ENC*2;       // 51.38MB
    __hip_bfloat16* emb_bf= (__hip_bfloat16*)(wsb + off); off += (size_t)10000*EMB*2;     // 10.24MB
    __hip_bfloat16* Wfrag = (__hip_bfloat16*)(wsb + off); off += (size_t)4*HID*KTOT*2;    // 29.36MB
    __hip_bfloat16* W2    = (__hip_bfloat16*)(wsb + off); off += (size_t)N2*HID*2;        // 5.24MB
    __hip_bfloat16* Wea_bf= (__hip_bfloat16*)(wsb + off); off += (size_t)ATT*ENC*2;       // 2.10MB (prologue-only)
    float* bsum  = (float*)(wsb + off); off += 4*HID*4;
    float* bias2 = (float*)(wsb + off); off += N2*4;
    float* hA    = (float*)(wsb + off); off += B*HID*4;
    float* hB    = (float*)(wsb + off); off += B*HID*4;
    float* cWs   = (float*)(wsb + off); off += B*HID*4;
    float* D2    = (float*)(wsb + off); off += (size_t)B*N2*4;
    __hip_bfloat16* gcR = (__hip_bfloat16*)(wsb + off); off += (size_t)T*B*ENC*2;         // 41.9MB rotating
    __hip_bfloat16* hbR = (__hip_bfloat16*)(wsb + off); off += (size_t)(T+1)*B*HID*2;     // 21.1MB rotating

    k_sort<<<1, 64, 0, stream>>>(lens, idxW, rankW, barCnt, nActW);
    k_init_hc<<<B, 256, 0, stream>>>(enc_h, enc_c, idxW, hA, cWs, hbR);
    k_cvt_wcat<<<57344, 256, 0, stream>>>(Wih, Whh, Wfrag);
    k_bsum<<<16, 256, 0, stream>>>(bih, bhh, bsum);
    k_cvt_w2<<<N2, 256, 0, stream>>>(Wda, bda, Wfb, bfb, W2, bias2);
    k_cvt_emb<<<20000, 256, 0, stream>>>(emb, emb_bf);
    k_cvt_wea<<<ATT, 256, 0, stream>>>(Wea, Wea_bf);
    k_cvt_img<<<dim3(P*ENC/256, B), 256, 0, stream>>>(img, idxW, img_s);
    k_att1m<<<dim3((B*P)/64, ATT/64), 256, 0, stream>>>(img_s, Wea_bf, bea, att1w);

    SP sp;
    sp.att1w = att1w; sp.img_s = img_s; sp.emb_bf = emb_bf; sp.Wfrag = Wfrag; sp.W2 = W2;
    sp.bsum = bsum; sp.bias2 = bias2; sp.wfa = wfa; sp.bfa = bfa;
    sp.sent = sent; sp.idx = idxW; sp.rank = rankW; sp.lens = lens; sp.nAct = nActW;
    sp.D2 = D2; sp.gcR = gcR; sp.hbR = hbR;
    sp.hF0 = hA; sp.hF1 = hB; sp.cW = cWs;
    sp.outH = outH; sp.outA = outA;
    sp.barCnt = barCnt;

    void* args[] = { &sp };
    hipLaunchCooperativeKernel(reinterpret_cast<void*>(k_scan), dim3(NBLK), dim3(NTHR),
                               args, 0, stream);
}